// Round 6
// baseline (586.203 us; speedup 1.0000x reference)
//
#include <hip/hip_runtime.h>
#include <stdint.h>

#define DEVI __device__ __forceinline__

typedef __attribute__((ext_vector_type(8))) uint16_t u16x8;
typedef __attribute__((ext_vector_type(4))) uint16_t u16x4v;
typedef __attribute__((ext_vector_type(8))) __bf16 bf16x8;
typedef __attribute__((ext_vector_type(4))) float f32x4;

DEVI uint16_t f2bf(float x) {
  union { float f; uint32_t u; } v; v.f = x;
  return (uint16_t)((v.u + 0x7fffu + ((v.u >> 16) & 1u)) >> 16);
}

DEVI uint16_t f2bfn(float f) {
  __bf16 h = (__bf16)f;
  return __builtin_bit_cast(uint16_t, h);
}

DEVI f32x4 mfma16(u16x8 a, u16x8 b, f32x4 c) {
  return __builtin_amdgcn_mfma_f32_16x16x32_bf16(
      __builtin_bit_cast(bf16x8, a), __builtin_bit_cast(bf16x8, b), c, 0, 0, 0);
}

DEVI void async16(void* lds, const void* g) {
  __builtin_amdgcn_global_load_lds(
      (const __attribute__((address_space(1))) uint32_t*)g,
      (__attribute__((address_space(3))) uint32_t*)lds, 16, 0, 0);
}

// 1/sqrt(128) * log2(e): softmax computed in exp2 domain, scale folded into Q.
#define QSC 0.12751742925f

// ---------------- elementwise f32 -> bf16 ----------------
__global__ void cvt_f32_bf16(const float* __restrict__ in, uint16_t* __restrict__ out, int n4) {
  int i = blockIdx.x * blockDim.x + threadIdx.x;
  const int st = gridDim.x * blockDim.x;
  for (; i < n4; i += st) {
    float4 v = ((const float4*)in)[i];
    u16x4v o;
    o[0] = f2bf(v.x); o[1] = f2bf(v.y); o[2] = f2bf(v.z); o[3] = f2bf(v.w);
    ((u16x4v*)out)[i] = o;
  }
}

// ------------- transpose + convert: f32 [K][N] -> bf16 [N][K] -------------
__global__ void transp_cvt(const float* __restrict__ in, uint16_t* __restrict__ out,
                           int K, int N) {
  __shared__ float Ws[64][65];
  const int n0 = blockIdx.x * 64, k0 = blockIdx.y * 64;
  const int t = threadIdx.x;
  const int r = t >> 4, c = (t & 15) << 2;
#pragma unroll
  for (int it = 0; it < 4; ++it) {
    float4 v = *(const float4*)&in[(size_t)(k0 + it * 16 + r) * N + n0 + c];
    Ws[it * 16 + r][c] = v.x; Ws[it * 16 + r][c + 1] = v.y;
    Ws[it * 16 + r][c + 2] = v.z; Ws[it * 16 + r][c + 3] = v.w;
  }
  __syncthreads();
#pragma unroll
  for (int it = 0; it < 4; ++it) {
    const int rr = it * 16 + r;   // n index in tile
    const int cc = c;             // k index in tile
    ushort4 o;
    o.x = f2bf(Ws[cc][rr]);     o.y = f2bf(Ws[cc + 1][rr]);
    o.z = f2bf(Ws[cc + 2][rr]); o.w = f2bf(Ws[cc + 3][rr]);
    *(ushort4*)&out[(size_t)(n0 + rr) * K + k0 + cc] = o;
  }
}

// ---- transpose bf16: [BH][T][128] -> [BH][128][T] (plain layout) ----
__global__ void transp_v(const uint16_t* __restrict__ in, uint16_t* __restrict__ out, int T) {
  __shared__ uint16_t Vsm[64][72];
  const int t0 = blockIdx.x * 64, d0 = blockIdx.y * 64, bh = blockIdx.z;
  const uint16_t* ip = in + (size_t)bh * T * 128;
  uint16_t* op = out + (size_t)bh * 128 * T;
  const int t = threadIdx.x;
  const int r = t >> 3, c = (t & 7) << 3;
#pragma unroll
  for (int it = 0; it < 2; ++it) {
    u16x8 v = *(const u16x8*)&ip[(size_t)(t0 + it * 32 + r) * 128 + d0 + c];
#pragma unroll
    for (int j = 0; j < 8; ++j) Vsm[it * 32 + r][c + j] = v[j];
  }
  __syncthreads();
#pragma unroll
  for (int it = 0; it < 2; ++it) {
    const int rr = it * 32 + r;  // d index in tile
    const int cc = c;            // t index in tile
    u16x8 o;
#pragma unroll
    for (int j = 0; j < 8; ++j) o[j] = Vsm[cc + j][rr];
    *(u16x8*)&op[(size_t)(d0 + rr) * T + t0 + cc] = o;
  }
}

// ------------- GEMM: C[M][N] = A[M][K] * Bt[N][K]^T + bias -------------
// EPI==0: scatter bf16 into q (scaled by QSC) / k / v layouts (plain).
// EPI==1: f32 out[M][N].
template <int EPI>
__global__ __launch_bounds__(256, 2)
void gemm_bt(const uint16_t* __restrict__ A, const uint16_t* __restrict__ Bt,
             const float* __restrict__ bias, float* __restrict__ outF,
             uint16_t* __restrict__ q, uint16_t* __restrict__ kk, uint16_t* __restrict__ v,
             int M, int N, int K) {
  constexpr int BK = 32;
  __shared__ uint16_t As[128 * BK];
  __shared__ uint16_t Bs[128 * BK];
  // bijective XCD swizzle (grid sizes here are multiples of 8)
  int bid = (int)blockIdx.x;
  const int q8 = (int)gridDim.x >> 3;
  bid = (bid & 7) * q8 + (bid >> 3);
  const int nbn = N >> 7;
  const int brow = (bid / nbn) << 7;
  const int bcol = (bid % nbn) << 7;
  const int t = threadIdx.x;
  const int w = t >> 6, lane = t & 63;
  const int wr = ((w >> 1) << 6), wc = ((w & 1) << 6);
  const int lr = lane & 15, lk = (lane >> 4) << 3;
  const int sr = t >> 2;
  const int sc = (t & 3) << 3;

  f32x4 acc[4][4];
#pragma unroll
  for (int i = 0; i < 4; ++i)
#pragma unroll
    for (int j = 0; j < 4; ++j) acc[i][j] = f32x4{0.f, 0.f, 0.f, 0.f};

  const uint16_t* Ap = A + (size_t)(brow + sr) * K + sc;
  const uint16_t* Bp = Bt + (size_t)(bcol + sr) * K + sc;
  const size_t rowskip = (size_t)64 * K;

  for (int k0 = 0; k0 < K; k0 += BK) {
    async16(&As[sr * BK + sc], Ap + k0);
    async16(&As[(64 + sr) * BK + sc], Ap + rowskip + k0);
    async16(&Bs[sr * BK + sc], Bp + k0);
    async16(&Bs[(64 + sr) * BK + sc], Bp + rowskip + k0);
    __syncthreads();
    u16x8 af[4], bf[4];
#pragma unroll
    for (int i = 0; i < 4; ++i) af[i] = *(const u16x8*)&As[(wr + i * 16 + lr) * BK + lk];
#pragma unroll
    for (int j = 0; j < 4; ++j) bf[j] = *(const u16x8*)&Bs[(wc + j * 16 + lr) * BK + lk];
#pragma unroll
    for (int i = 0; i < 4; ++i)
#pragma unroll
      for (int j = 0; j < 4; ++j) acc[i][j] = mfma16(af[i], bf[j], acc[i][j]);
    __syncthreads();
  }

#pragma unroll
  for (int i = 0; i < 4; ++i) {
#pragma unroll
    for (int j = 0; j < 4; ++j) {
      const int col = bcol + wc + j * 16 + lr;
      const float bb = bias[col];
#pragma unroll
      for (int r = 0; r < 4; ++r) {
        const int row = brow + wr + i * 16 + ((lane >> 4) << 2) + r;
        const float val = acc[i][j][r] + bb;
        if (EPI == 1) {
          outF[(size_t)row * N + col] = val;
        } else {
          const int b_ = row >> 11, tt = row & 2047;
          const int d = col & 127;
          if (col < 2048) {
            const int hh = col >> 7;
            q[((size_t)((b_ * 16 + hh) * 2048 + tt) << 7) + d] = f2bf(val * QSC);
          } else if (col < 2560) {
            const int hh = (col - 2048) >> 7;
            kk[((size_t)((b_ * 4 + hh) * 2048 + tt) << 7) + d] = f2bf(val);
          } else {
            const int hh = (col - 2560) >> 7;
            v[((size_t)((b_ * 4 + hh) * 2048 + tt) << 7) + d] = f2bf(val);
          }
        }
      }
    }
  }
}

// ------------- flash attention (causal, GQA 4:1), swapped-QK^T -------------
// T3 2-phase pipeline: K/V double-buffered in LDS via global_load_lds(16B),
// loads for tile t+1 issued BEFORE compute(t), ONE barrier per tile (the
// compiler's vmcnt(0)+barrier at __syncthreads is exactly the drain we want,
// placed AFTER compute). Swizzle per rule #21: linear LDS dest + inverse-
// swizzled GLOBAL source + XOR on ds_read. LDS = 32+32+16 = 80 KB -> 2 blk/CU.
__global__ __launch_bounds__(256, 1)
void attn_fwd(const uint16_t* __restrict__ Q,   // [B*16][T][128], pre-scaled by QSC
              const uint16_t* __restrict__ Kg,  // [B*4][T][128]
              const uint16_t* __restrict__ Vt,  // [B*4][128][T]
              uint16_t* __restrict__ Y,         // [B*T][2048], col offset h*128
              int T) {
  __shared__ __align__(16) uint16_t Ks[2][64 * 128];   // 32 KB
  __shared__ __align__(16) uint16_t Vs[2][128 * 64];   // 32 KB
  __shared__ __align__(16) uint16_t Ps[8][16][64];     // 16 KB, XOR-swizzled cols
  const int qb = (int)gridDim.x - 1 - (int)blockIdx.x;  // heavy first
  const int h = blockIdx.y, b = blockIdx.z;
  const int hkv = h >> 2;

  const int t = threadIdx.x, w = t >> 6, lane = t & 63;
  const int lr = lane & 15, g = lane >> 4, lk = g << 3;
  const int swz = (lr & 7) << 3;

  const uint16_t* Qp = Q + ((size_t)(b * 16 + h) * T + qb * 128) * 128;
  const uint16_t* Kp = Kg + (size_t)(b * 4 + hkv) * T * 128;
  const uint16_t* Vp = Vt + (size_t)(b * 4 + hkv) * 128 * T;

  // staging: per wave 4 K-insts (rows w*16+4it.. , lane-linear 16B) and
  // 4 V-insts (rows w*32+8it..). Global source col pre-XORed by (row&7)<<3.
  auto stage = [&](int buf, int kv0) {
#pragma unroll
    for (int it = 0; it < 4; ++it) {
      const int krow = w * 16 + it * 4 + (lane >> 4);
      const int kcol = ((lane & 15) << 3) ^ ((krow & 7) << 3);
      async16(&Ks[buf][((w * 16 + it * 4) << 7) + (lane << 3)],
              &Kp[(size_t)(kv0 + krow) * 128 + kcol]);
    }
#pragma unroll
    for (int it = 0; it < 4; ++it) {
      const int vrow = w * 32 + it * 8 + (lane >> 3);
      const int vcol = ((lane & 7) << 3) ^ ((vrow & 7) << 3);
      async16(&Vs[buf][((w * 32 + it * 8) << 6) + (lane << 3)],
              &Vp[(size_t)vrow * T + kv0 + vcol]);
    }
  };

  // Q fragments (B-operand): lane holds Q[row0+mf*16+lr][kf*32+lk .. +7]
  u16x8 qf[2][4];
#pragma unroll
  for (int mf = 0; mf < 2; ++mf)
#pragma unroll
    for (int kf = 0; kf < 4; ++kf)
      qf[mf][kf] = *(const u16x8*)&Qp[(size_t)(w * 32 + mf * 16 + lr) * 128 + kf * 32 + lk];

  f32x4 o[2][8];  // O^T: lane holds O[q=lr][d = dtile*16 + g*4 + r]
  float mrow[2] = {-3e38f, -3e38f}, lrow[2] = {0.f, 0.f};
#pragma unroll
  for (int mf = 0; mf < 2; ++mf)
#pragma unroll
    for (int d = 0; d < 8; ++d) o[mf][d] = f32x4{0.f, 0.f, 0.f, 0.f};

  const int row0 = qb * 128 + w * 32;
  const int ntiles = 2 * qb + 2;
  const int myn = 2 * qb + 1 + (w >> 1);  // waves 0,1 skip last (fully-masked) tile

  stage(0, 0);
  __syncthreads();  // compiler emits vmcnt(0) drain here

  int cur = 0;
  for (int tile = 0; tile < ntiles; ++tile) {
    // issue loads for tile t+1 into the other buffer (fly under compute)
    if (tile + 1 < ntiles) stage(cur ^ 1, (tile + 1) << 6);

    if (tile < myn) {
      const int kv0 = tile << 6;
      // S^T[k][q=lr]
      f32x4 s2[2][4];
#pragma unroll
      for (int mf = 0; mf < 2; ++mf)
#pragma unroll
        for (int m = 0; m < 4; ++m) s2[mf][m] = f32x4{0.f, 0.f, 0.f, 0.f};
      __builtin_amdgcn_s_setprio(1);
#pragma unroll
      for (int kf = 0; kf < 4; ++kf) {
        const int cc = (kf * 32 + lk) ^ swz;
#pragma unroll
        for (int m = 0; m < 4; ++m) {
          u16x8 kfr = *(const u16x8*)&Ks[cur][(m * 16 + lr) * 128 + cc];
          s2[0][m] = mfma16(kfr, qf[0][kf], s2[0][m]);
          s2[1][m] = mfma16(kfr, qf[1][kf], s2[1][m]);
        }
      }
      __builtin_amdgcn_s_setprio(0);
      float scl[2];
#pragma unroll
      for (int mf = 0; mf < 2; ++mf) {
        if (kv0 + 63 > row0 + mf * 16) {  // wave-uniform mask check
          const int qrow = row0 + mf * 16 + lr;
#pragma unroll
          for (int m = 0; m < 4; ++m)
#pragma unroll
            for (int r = 0; r < 4; ++r)
              if (kv0 + m * 16 + (g << 2) + r > qrow) s2[mf][m][r] = -3e38f;
        }
        float mx = s2[mf][0][0];
#pragma unroll
        for (int m = 0; m < 4; ++m)
#pragma unroll
          for (int r = 0; r < 4; ++r) mx = fmaxf(mx, s2[mf][m][r]);
        mx = fmaxf(mx, __shfl_xor(mx, 16));
        mx = fmaxf(mx, __shfl_xor(mx, 32));
        const float mnew = fmaxf(mrow[mf], mx);
        const float sc = exp2f(mrow[mf] - mnew);
        float ps = 0.f;
#pragma unroll
        for (int m = 0; m < 4; ++m) {
          u16x4v pk;
#pragma unroll
          for (int r = 0; r < 4; ++r) {
            const float p = exp2f(s2[mf][m][r] - mnew);
            ps += p;
            pk[r] = f2bfn(p);
          }
          *(u16x4v*)&Ps[w * 2 + mf][lr][(m * 16 + (g << 2)) ^ swz] = pk;
        }
        ps += __shfl_xor(ps, 16);
        ps += __shfl_xor(ps, 32);
        mrow[mf] = mnew;
        lrow[mf] = lrow[mf] * sc + ps;
        scl[mf] = sc;
      }
#pragma unroll
      for (int mf = 0; mf < 2; ++mf)
#pragma unroll
        for (int d = 0; d < 8; ++d)
#pragma unroll
          for (int r = 0; r < 4; ++r) o[mf][d][r] *= scl[mf];

      u16x8 pa0[2], pa1[2];
#pragma unroll
      for (int kf = 0; kf < 2; ++kf) {
        pa0[kf] = *(const u16x8*)&Ps[w * 2][lr][(kf * 32 + lk) ^ swz];
        pa1[kf] = *(const u16x8*)&Ps[w * 2 + 1][lr][(kf * 32 + lk) ^ swz];
      }
      __builtin_amdgcn_s_setprio(1);
#pragma unroll
      for (int d = 0; d < 8; ++d) {
#pragma unroll
        for (int kf = 0; kf < 2; ++kf) {
          u16x8 vb = *(const u16x8*)&Vs[cur][(d * 16 + lr) * 64 + ((kf * 32 + lk) ^ swz)];
          o[0][d] = mfma16(vb, pa0[kf], o[0][d]);
          o[1][d] = mfma16(vb, pa1[kf], o[1][d]);
        }
      }
      __builtin_amdgcn_s_setprio(0);
    }
    __syncthreads();  // single barrier: drains this tile's prefetch, syncs buf reuse
    cur ^= 1;
  }

  uint16_t* Yp = Y + ((size_t)(b * T + row0)) * 2048 + h * 128;
#pragma unroll
  for (int mf = 0; mf < 2; ++mf) {
    const float inv = 1.f / lrow[mf];
#pragma unroll
    for (int d = 0; d < 8; ++d) {
      u16x4v pk;
#pragma unroll
      for (int r = 0; r < 4; ++r) pk[r] = f2bfn(o[mf][d][r] * inv);
      *(u16x4v*)&Yp[(size_t)(mf * 16 + lr) * 2048 + d * 16 + (g << 2)] = pk;
    }
  }
}

extern "C" void kernel_launch(void* const* d_in, const int* in_sizes, int n_in,
                              void* d_out, int out_size, void* d_ws, size_t ws_size,
                              hipStream_t stream) {
  const float* x      = (const float*)d_in[0];
  const float* W_attn = (const float*)d_in[1];
  const float* b_attn = (const float*)d_in[2];
  const float* W_proj = (const float*)d_in[3];
  const float* b_proj = (const float*)d_in[4];
  float* out = (float*)d_out;

  const int B = 4, T = 2048, C = 2048, H = 16, HKV = 4, HS = 128;
  const int M = B * T;               // 8192
  const int Nqkv = C + 2 * HKV * HS; // 3072

  uint8_t* ws = (uint8_t*)d_ws;
  size_t off = 0;
  auto alloc = [&](size_t bytes) {
    void* p = ws + off;
    off += (bytes + 255) & ~(size_t)255;
    return p;
  };
  uint16_t* xb  = (uint16_t*)alloc((size_t)M * C * 2);      // reused as yb after qkv
  uint16_t* WaT = (uint16_t*)alloc((size_t)Nqkv * C * 2);
  uint16_t* WpT = (uint16_t*)alloc((size_t)C * C * 2);
  uint16_t* qb  = (uint16_t*)alloc((size_t)B * H * T * HS * 2);
  uint16_t* kb  = (uint16_t*)alloc((size_t)B * HKV * T * HS * 2);
  uint16_t* vb  = (uint16_t*)alloc((size_t)B * HKV * T * HS * 2);
  uint16_t* vtb = (uint16_t*)alloc((size_t)B * HKV * HS * T * 2);
  uint16_t* yb  = xb;

  cvt_f32_bf16<<<2048, 256, 0, stream>>>(x, xb, M * C / 4);
  transp_cvt<<<dim3(Nqkv / 64, C / 64), 256, 0, stream>>>(W_attn, WaT, C, Nqkv);
  transp_cvt<<<dim3(C / 64, C / 64), 256, 0, stream>>>(W_proj, WpT, C, C);
  gemm_bt<0><<<dim3((M / 128) * (Nqkv / 128)), 256, 0, stream>>>(
      xb, WaT, b_attn, nullptr, qb, kb, vb, M, Nqkv, C);
  transp_v<<<dim3(T / 64, 2, B * HKV), 256, 0, stream>>>(vb, vtb, T);
  attn_fwd<<<dim3(T / 128, H, B), 256, 0, stream>>>(qb, kb, vtb, yb, T);
  gemm_bt<1><<<dim3((M / 128) * (C / 128)), 256, 0, stream>>>(
      yb, WpT, b_proj, out, nullptr, nullptr, nullptr, M, C, C);
}

// Round 7
// 441.475 us; speedup vs baseline: 1.3278x; 1.3278x over previous
//
#include <hip/hip_runtime.h>
#include <stdint.h>

#define DEVI __device__ __forceinline__

typedef __attribute__((ext_vector_type(8))) uint16_t u16x8;
typedef __attribute__((ext_vector_type(4))) uint16_t u16x4v;
typedef __attribute__((ext_vector_type(8))) __bf16 bf16x8;
typedef __attribute__((ext_vector_type(4))) float f32x4;

DEVI uint16_t f2bf(float x) {
  union { float f; uint32_t u; } v; v.f = x;
  return (uint16_t)((v.u + 0x7fffu + ((v.u >> 16) & 1u)) >> 16);
}

DEVI uint16_t f2bfn(float f) {
  __bf16 h = (__bf16)f;
  return __builtin_bit_cast(uint16_t, h);
}

DEVI f32x4 mfma16(u16x8 a, u16x8 b, f32x4 c) {
  return __builtin_amdgcn_mfma_f32_16x16x32_bf16(
      __builtin_bit_cast(bf16x8, a), __builtin_bit_cast(bf16x8, b), c, 0, 0, 0);
}

DEVI void async16(void* lds, const void* g) {
  __builtin_amdgcn_global_load_lds(
      (const __attribute__((address_space(1))) uint32_t*)g,
      (__attribute__((address_space(3))) uint32_t*)lds, 16, 0, 0);
}

// 1/sqrt(128) * log2(e): softmax computed in exp2 domain, scale folded into Q.
#define QSC 0.12751742925f

// ---------------- elementwise f32 -> bf16 ----------------
__global__ void cvt_f32_bf16(const float* __restrict__ in, uint16_t* __restrict__ out, int n4) {
  int i = blockIdx.x * blockDim.x + threadIdx.x;
  const int st = gridDim.x * blockDim.x;
  for (; i < n4; i += st) {
    float4 v = ((const float4*)in)[i];
    u16x4v o;
    o[0] = f2bf(v.x); o[1] = f2bf(v.y); o[2] = f2bf(v.z); o[3] = f2bf(v.w);
    ((u16x4v*)out)[i] = o;
  }
}

// ------------- transpose + convert: f32 [K][N] -> bf16 [N][K] -------------
__global__ void transp_cvt(const float* __restrict__ in, uint16_t* __restrict__ out,
                           int K, int N) {
  __shared__ float Ws[64][65];
  const int n0 = blockIdx.x * 64, k0 = blockIdx.y * 64;
  const int t = threadIdx.x;
  const int r = t >> 4, c = (t & 15) << 2;
#pragma unroll
  for (int it = 0; it < 4; ++it) {
    float4 v = *(const float4*)&in[(size_t)(k0 + it * 16 + r) * N + n0 + c];
    Ws[it * 16 + r][c] = v.x; Ws[it * 16 + r][c + 1] = v.y;
    Ws[it * 16 + r][c + 2] = v.z; Ws[it * 16 + r][c + 3] = v.w;
  }
  __syncthreads();
#pragma unroll
  for (int it = 0; it < 4; ++it) {
    const int rr = it * 16 + r;   // n index in tile
    const int cc = c;             // k index in tile
    ushort4 o;
    o.x = f2bf(Ws[cc][rr]);     o.y = f2bf(Ws[cc + 1][rr]);
    o.z = f2bf(Ws[cc + 2][rr]); o.w = f2bf(Ws[cc + 3][rr]);
    *(ushort4*)&out[(size_t)(n0 + rr) * K + k0 + cc] = o;
  }
}

// ---- transpose bf16: [BH][T][128] -> [BH][128][T] (plain layout) ----
__global__ void transp_v(const uint16_t* __restrict__ in, uint16_t* __restrict__ out, int T) {
  __shared__ uint16_t Vsm[64][72];
  const int t0 = blockIdx.x * 64, d0 = blockIdx.y * 64, bh = blockIdx.z;
  const uint16_t* ip = in + (size_t)bh * T * 128;
  uint16_t* op = out + (size_t)bh * 128 * T;
  const int t = threadIdx.x;
  const int r = t >> 3, c = (t & 7) << 3;
#pragma unroll
  for (int it = 0; it < 2; ++it) {
    u16x8 v = *(const u16x8*)&ip[(size_t)(t0 + it * 32 + r) * 128 + d0 + c];
#pragma unroll
    for (int j = 0; j < 8; ++j) Vsm[it * 32 + r][c + j] = v[j];
  }
  __syncthreads();
#pragma unroll
  for (int it = 0; it < 2; ++it) {
    const int rr = it * 32 + r;  // d index in tile
    const int cc = c;            // t index in tile
    u16x8 o;
#pragma unroll
    for (int j = 0; j < 8; ++j) o[j] = Vsm[cc + j][rr];
    *(u16x8*)&op[(size_t)(d0 + rr) * T + t0 + cc] = o;
  }
}

// ------------- GEMM: C[M][N] = A[M][K] * Bt[N][K]^T + bias -------------
// EPI==0: scatter bf16 into q (scaled by QSC) / k / v layouts (plain).
// EPI==1: f32 out[M][N].
template <int EPI>
__global__ __launch_bounds__(256, 2)
void gemm_bt(const uint16_t* __restrict__ A, const uint16_t* __restrict__ Bt,
             const float* __restrict__ bias, float* __restrict__ outF,
             uint16_t* __restrict__ q, uint16_t* __restrict__ kk, uint16_t* __restrict__ v,
             int M, int N, int K) {
  constexpr int BK = 32;
  __shared__ uint16_t As[128 * BK];
  __shared__ uint16_t Bs[128 * BK];
  // bijective XCD swizzle (grid sizes here are multiples of 8)
  int bid = (int)blockIdx.x;
  const int q8 = (int)gridDim.x >> 3;
  bid = (bid & 7) * q8 + (bid >> 3);
  const int nbn = N >> 7;
  const int brow = (bid / nbn) << 7;
  const int bcol = (bid % nbn) << 7;
  const int t = threadIdx.x;
  const int w = t >> 6, lane = t & 63;
  const int wr = ((w >> 1) << 6), wc = ((w & 1) << 6);
  const int lr = lane & 15, lk = (lane >> 4) << 3;
  const int sr = t >> 2;
  const int sc = (t & 3) << 3;

  f32x4 acc[4][4];
#pragma unroll
  for (int i = 0; i < 4; ++i)
#pragma unroll
    for (int j = 0; j < 4; ++j) acc[i][j] = f32x4{0.f, 0.f, 0.f, 0.f};

  const uint16_t* Ap = A + (size_t)(brow + sr) * K + sc;
  const uint16_t* Bp = Bt + (size_t)(bcol + sr) * K + sc;
  const size_t rowskip = (size_t)64 * K;

  for (int k0 = 0; k0 < K; k0 += BK) {
    async16(&As[sr * BK + sc], Ap + k0);
    async16(&As[(64 + sr) * BK + sc], Ap + rowskip + k0);
    async16(&Bs[sr * BK + sc], Bp + k0);
    async16(&Bs[(64 + sr) * BK + sc], Bp + rowskip + k0);
    __syncthreads();
    u16x8 af[4], bf[4];
#pragma unroll
    for (int i = 0; i < 4; ++i) af[i] = *(const u16x8*)&As[(wr + i * 16 + lr) * BK + lk];
#pragma unroll
    for (int j = 0; j < 4; ++j) bf[j] = *(const u16x8*)&Bs[(wc + j * 16 + lr) * BK + lk];
#pragma unroll
    for (int i = 0; i < 4; ++i)
#pragma unroll
      for (int j = 0; j < 4; ++j) acc[i][j] = mfma16(af[i], bf[j], acc[i][j]);
    __syncthreads();
  }

#pragma unroll
  for (int i = 0; i < 4; ++i) {
#pragma unroll
    for (int j = 0; j < 4; ++j) {
      const int col = bcol + wc + j * 16 + lr;
      const float bb = bias[col];
#pragma unroll
      for (int r = 0; r < 4; ++r) {
        const int row = brow + wr + i * 16 + ((lane >> 4) << 2) + r;
        const float val = acc[i][j][r] + bb;
        if (EPI == 1) {
          outF[(size_t)row * N + col] = val;
        } else {
          const int b_ = row >> 11, tt = row & 2047;
          const int d = col & 127;
          if (col < 2048) {
            const int hh = col >> 7;
            q[((size_t)((b_ * 16 + hh) * 2048 + tt) << 7) + d] = f2bf(val * QSC);
          } else if (col < 2560) {
            const int hh = (col - 2048) >> 7;
            kk[((size_t)((b_ * 4 + hh) * 2048 + tt) << 7) + d] = f2bf(val);
          } else {
            const int hh = (col - 2560) >> 7;
            v[((size_t)((b_ * 4 + hh) * 2048 + tt) << 7) + d] = f2bf(val);
          }
        }
      }
    }
  }
}

// ------------- flash attention (causal, GQA 4:1), swapped-QK^T -------------
// DIAGONAL PAIRING: grid (8,16,4); block pr handles qb=15-pr then qb=pr ->
// every block does exactly 34 KV tiles. 512 uniform blocks = 2/CU (80KB LDS),
// all resident start-to-end (round 6: 1024 imbalanced blocks gave 6.5% occ =
// ~0.5 blocks/CU avg; the tail was the whole kernel).
// Inside: round-6 T3 pipeline (K/V dbuf, global_load_lds(16B), prefetch t+1
// before compute(t), one barrier/tile; rule-#21 swizzle = linear LDS dest +
// inverse-swizzled global src + XOR on read).
__global__ __launch_bounds__(256, 1)
void attn_fwd(const uint16_t* __restrict__ Q,   // [B*16][T][128], pre-scaled by QSC
              const uint16_t* __restrict__ Kg,  // [B*4][T][128]
              const uint16_t* __restrict__ Vt,  // [B*4][128][T]
              uint16_t* __restrict__ Y,         // [B*T][2048], col offset h*128
              int T) {
  __shared__ __align__(16) uint16_t Ks[2][64 * 128];   // 32 KB
  __shared__ __align__(16) uint16_t Vs[2][128 * 64];   // 32 KB
  __shared__ __align__(16) uint16_t Ps[8][16][64];     // 16 KB, XOR-swizzled cols
  const int pr = blockIdx.x;                  // 0..7
  const int h = blockIdx.y, b = blockIdx.z;
  const int hkv = h >> 2;

  const int t = threadIdx.x, w = t >> 6, lane = t & 63;
  const int lr = lane & 15, g = lane >> 4, lk = g << 3;
  const int swz = (lr & 7) << 3;

  const uint16_t* Qh = Q + (size_t)(b * 16 + h) * T * 128;
  const uint16_t* Kp = Kg + (size_t)(b * 4 + hkv) * T * 128;
  const uint16_t* Vp = Vt + (size_t)(b * 4 + hkv) * 128 * T;

  // staging: per wave 4 K-insts (rows w*16+4it.., lane-linear 16B) and
  // 4 V-insts (rows w*32+8it..). Global source col pre-XORed by (row&7)<<3.
  auto stage = [&](int buf, int kv0) {
#pragma unroll
    for (int it = 0; it < 4; ++it) {
      const int krow = w * 16 + it * 4 + (lane >> 4);
      const int kcol = ((lane & 15) << 3) ^ ((krow & 7) << 3);
      async16(&Ks[buf][((w * 16 + it * 4) << 7) + (lane << 3)],
              &Kp[(size_t)(kv0 + krow) * 128 + kcol]);
    }
#pragma unroll
    for (int it = 0; it < 4; ++it) {
      const int vrow = w * 32 + it * 8 + (lane >> 3);
      const int vcol = ((lane & 7) << 3) ^ ((vrow & 7) << 3);
      async16(&Vs[buf][((w * 32 + it * 8) << 6) + (lane << 3)],
              &Vp[(size_t)vrow * T + kv0 + vcol]);
    }
  };

  for (int half = 0; half < 2; ++half) {
    const int qb = half == 0 ? 15 - pr : pr;
    const uint16_t* Qp = Qh + (size_t)(qb * 128) * 128;

    // Q fragments (B-operand): lane holds Q[row0+mf*16+lr][kf*32+lk .. +7]
    u16x8 qf[2][4];
#pragma unroll
    for (int mf = 0; mf < 2; ++mf)
#pragma unroll
      for (int kf = 0; kf < 4; ++kf)
        qf[mf][kf] = *(const u16x8*)&Qp[(size_t)(w * 32 + mf * 16 + lr) * 128 + kf * 32 + lk];

    f32x4 o[2][8];  // O^T: lane holds O[q=lr][d = dtile*16 + g*4 + r]
    float mrow[2] = {-3e38f, -3e38f}, lrow[2] = {0.f, 0.f};
#pragma unroll
    for (int mf = 0; mf < 2; ++mf)
#pragma unroll
      for (int d = 0; d < 8; ++d) o[mf][d] = f32x4{0.f, 0.f, 0.f, 0.f};

    const int row0 = qb * 128 + w * 32;
    const int ntiles = 2 * qb + 2;
    const int myn = 2 * qb + 1 + (w >> 1);  // waves 0,1 skip last (fully-masked) tile

    stage(0, 0);
    __syncthreads();  // compiler emits vmcnt(0) drain here

    int cur = 0;
    for (int tile = 0; tile < ntiles; ++tile) {
      // issue loads for tile t+1 into the other buffer (fly under compute)
      if (tile + 1 < ntiles) stage(cur ^ 1, (tile + 1) << 6);

      if (tile < myn) {
        const int kv0 = tile << 6;
        // S^T[k][q=lr]
        f32x4 s2[2][4];
#pragma unroll
        for (int mf = 0; mf < 2; ++mf)
#pragma unroll
          for (int m = 0; m < 4; ++m) s2[mf][m] = f32x4{0.f, 0.f, 0.f, 0.f};
        __builtin_amdgcn_s_setprio(1);
#pragma unroll
        for (int kf = 0; kf < 4; ++kf) {
          const int cc = (kf * 32 + lk) ^ swz;
#pragma unroll
          for (int m = 0; m < 4; ++m) {
            u16x8 kfr = *(const u16x8*)&Ks[cur][(m * 16 + lr) * 128 + cc];
            s2[0][m] = mfma16(kfr, qf[0][kf], s2[0][m]);
            s2[1][m] = mfma16(kfr, qf[1][kf], s2[1][m]);
          }
        }
        __builtin_amdgcn_s_setprio(0);
        float scl[2];
#pragma unroll
        for (int mf = 0; mf < 2; ++mf) {
          if (kv0 + 63 > row0 + mf * 16) {  // wave-uniform mask check
            const int qrow = row0 + mf * 16 + lr;
#pragma unroll
            for (int m = 0; m < 4; ++m)
#pragma unroll
              for (int r = 0; r < 4; ++r)
                if (kv0 + m * 16 + (g << 2) + r > qrow) s2[mf][m][r] = -3e38f;
          }
          float mx = s2[mf][0][0];
#pragma unroll
          for (int m = 0; m < 4; ++m)
#pragma unroll
            for (int r = 0; r < 4; ++r) mx = fmaxf(mx, s2[mf][m][r]);
          mx = fmaxf(mx, __shfl_xor(mx, 16));
          mx = fmaxf(mx, __shfl_xor(mx, 32));
          const float mnew = fmaxf(mrow[mf], mx);
          const float sc = exp2f(mrow[mf] - mnew);
          float ps = 0.f;
#pragma unroll
          for (int m = 0; m < 4; ++m) {
            u16x4v pk;
#pragma unroll
            for (int r = 0; r < 4; ++r) {
              const float p = exp2f(s2[mf][m][r] - mnew);
              ps += p;
              pk[r] = f2bfn(p);
            }
            *(u16x4v*)&Ps[w * 2 + mf][lr][(m * 16 + (g << 2)) ^ swz] = pk;
          }
          ps += __shfl_xor(ps, 16);
          ps += __shfl_xor(ps, 32);
          mrow[mf] = mnew;
          lrow[mf] = lrow[mf] * sc + ps;
          scl[mf] = sc;
        }
        // T13: skip the 64-FMA O-rescale when max is stable across all rows
        if (!__all(scl[0] == 1.f && scl[1] == 1.f)) {
#pragma unroll
          for (int mf = 0; mf < 2; ++mf)
#pragma unroll
            for (int d = 0; d < 8; ++d)
#pragma unroll
              for (int r = 0; r < 4; ++r) o[mf][d][r] *= scl[mf];
        }

        u16x8 pa0[2], pa1[2];
#pragma unroll
        for (int kf = 0; kf < 2; ++kf) {
          pa0[kf] = *(const u16x8*)&Ps[w * 2][lr][(kf * 32 + lk) ^ swz];
          pa1[kf] = *(const u16x8*)&Ps[w * 2 + 1][lr][(kf * 32 + lk) ^ swz];
        }
        __builtin_amdgcn_s_setprio(1);
#pragma unroll
        for (int d = 0; d < 8; ++d) {
#pragma unroll
          for (int kf = 0; kf < 2; ++kf) {
            u16x8 vb = *(const u16x8*)&Vs[cur][(d * 16 + lr) * 64 + ((kf * 32 + lk) ^ swz)];
            o[0][d] = mfma16(vb, pa0[kf], o[0][d]);
            o[1][d] = mfma16(vb, pa1[kf], o[1][d]);
          }
        }
        __builtin_amdgcn_s_setprio(0);
      }
      __syncthreads();  // single barrier: drains this tile's prefetch, syncs buf reuse
      cur ^= 1;
    }

    uint16_t* Yp = Y + ((size_t)(b * T + row0)) * 2048 + h * 128;
#pragma unroll
    for (int mf = 0; mf < 2; ++mf) {
      const float inv = 1.f / lrow[mf];
#pragma unroll
      for (int d = 0; d < 8; ++d) {
        u16x4v pk;
#pragma unroll
        for (int r = 0; r < 4; ++r) pk[r] = f2bfn(o[mf][d][r] * inv);
        *(u16x4v*)&Yp[(size_t)(mf * 16 + lr) * 2048 + d * 16 + (g << 2)] = pk;
      }
    }
    // no extra barrier needed: tile loop ended with __syncthreads(), and the
    // Y epilogue touches no LDS before the next half's stage().
  }
}

extern "C" void kernel_launch(void* const* d_in, const int* in_sizes, int n_in,
                              void* d_out, int out_size, void* d_ws, size_t ws_size,
                              hipStream_t stream) {
  const float* x      = (const float*)d_in[0];
  const float* W_attn = (const float*)d_in[1];
  const float* b_attn = (const float*)d_in[2];
  const float* W_proj = (const float*)d_in[3];
  const float* b_proj = (const float*)d_in[4];
  float* out = (float*)d_out;

  const int B = 4, T = 2048, C = 2048, H = 16, HKV = 4, HS = 128;
  const int M = B * T;               // 8192
  const int Nqkv = C + 2 * HKV * HS; // 3072

  uint8_t* ws = (uint8_t*)d_ws;
  size_t off = 0;
  auto alloc = [&](size_t bytes) {
    void* p = ws + off;
    off += (bytes + 255) & ~(size_t)255;
    return p;
  };
  uint16_t* xb  = (uint16_t*)alloc((size_t)M * C * 2);      // reused as yb after qkv
  uint16_t* WaT = (uint16_t*)alloc((size_t)Nqkv * C * 2);
  uint16_t* WpT = (uint16_t*)alloc((size_t)C * C * 2);
  uint16_t* qb  = (uint16_t*)alloc((size_t)B * H * T * HS * 2);
  uint16_t* kb  = (uint16_t*)alloc((size_t)B * HKV * T * HS * 2);
  uint16_t* vb  = (uint16_t*)alloc((size_t)B * HKV * T * HS * 2);
  uint16_t* vtb = (uint16_t*)alloc((size_t)B * HKV * HS * T * 2);
  uint16_t* yb  = xb;

  cvt_f32_bf16<<<2048, 256, 0, stream>>>(x, xb, M * C / 4);
  transp_cvt<<<dim3(Nqkv / 64, C / 64), 256, 0, stream>>>(W_attn, WaT, C, Nqkv);
  transp_cvt<<<dim3(C / 64, C / 64), 256, 0, stream>>>(W_proj, WpT, C, C);
  gemm_bt<0><<<dim3((M / 128) * (Nqkv / 128)), 256, 0, stream>>>(
      xb, WaT, b_attn, nullptr, qb, kb, vb, M, Nqkv, C);
  transp_v<<<dim3(T / 64, 2, B * HKV), 256, 0, stream>>>(vb, vtb, T);
  attn_fwd<<<dim3(8, H, B), 256, 0, stream>>>(qb, kb, vtb, yb, T);
  gemm_bt<1><<<dim3((M / 128) * (C / 128)), 256, 0, stream>>>(
      yb, WpT, b_proj, out, nullptr, nullptr, nullptr, M, C, C);
}

// Round 8
// 437.339 us; speedup vs baseline: 1.3404x; 1.0095x over previous
//
#include <hip/hip_runtime.h>
#include <stdint.h>

#define DEVI __device__ __forceinline__

typedef __attribute__((ext_vector_type(8))) uint16_t u16x8;
typedef __attribute__((ext_vector_type(4))) uint16_t u16x4v;
typedef __attribute__((ext_vector_type(4))) uint32_t u32x4;
typedef __attribute__((ext_vector_type(8))) __bf16 bf16x8;
typedef __attribute__((ext_vector_type(4))) float f32x4;
typedef __attribute__((ext_vector_type(16))) float f32x16;

DEVI uint16_t f2bf(float x) {
  union { float f; uint32_t u; } v; v.f = x;
  return (uint16_t)((v.u + 0x7fffu + ((v.u >> 16) & 1u)) >> 16);
}

DEVI uint16_t f2bfn(float f) {
  __bf16 h = (__bf16)f;
  return __builtin_bit_cast(uint16_t, h);
}

DEVI f32x4 mfma16(u16x8 a, u16x8 b, f32x4 c) {
  return __builtin_amdgcn_mfma_f32_16x16x32_bf16(
      __builtin_bit_cast(bf16x8, a), __builtin_bit_cast(bf16x8, b), c, 0, 0, 0);
}

DEVI f32x16 mfma32(u16x8 a, u16x8 b, f32x16 c) {
  return __builtin_amdgcn_mfma_f32_32x32x16_bf16(
      __builtin_bit_cast(bf16x8, a), __builtin_bit_cast(bf16x8, b), c, 0, 0, 0);
}

DEVI void async16(void* lds, const void* g) {
  __builtin_amdgcn_global_load_lds(
      (const __attribute__((address_space(1))) uint32_t*)g,
      (__attribute__((address_space(3))) uint32_t*)lds, 16, 0, 0);
}

// 1/sqrt(128) * log2(e): softmax computed in exp2 domain, scale folded into Q.
#define QSC 0.12751742925f

// ---------------- elementwise f32 -> bf16 ----------------
__global__ void cvt_f32_bf16(const float* __restrict__ in, uint16_t* __restrict__ out, int n4) {
  int i = blockIdx.x * blockDim.x + threadIdx.x;
  const int st = gridDim.x * blockDim.x;
  for (; i < n4; i += st) {
    float4 v = ((const float4*)in)[i];
    u16x4v o;
    o[0] = f2bf(v.x); o[1] = f2bf(v.y); o[2] = f2bf(v.z); o[3] = f2bf(v.w);
    ((u16x4v*)out)[i] = o;
  }
}

// ------------- transpose + convert: f32 [K][N] -> bf16 [N][K] -------------
__global__ void transp_cvt(const float* __restrict__ in, uint16_t* __restrict__ out,
                           int K, int N) {
  __shared__ float Ws[64][65];
  const int n0 = blockIdx.x * 64, k0 = blockIdx.y * 64;
  const int t = threadIdx.x;
  const int r = t >> 4, c = (t & 15) << 2;
#pragma unroll
  for (int it = 0; it < 4; ++it) {
    float4 v = *(const float4*)&in[(size_t)(k0 + it * 16 + r) * N + n0 + c];
    Ws[it * 16 + r][c] = v.x; Ws[it * 16 + r][c + 1] = v.y;
    Ws[it * 16 + r][c + 2] = v.z; Ws[it * 16 + r][c + 3] = v.w;
  }
  __syncthreads();
#pragma unroll
  for (int it = 0; it < 4; ++it) {
    const int rr = it * 16 + r;   // n index in tile
    const int cc = c;             // k index in tile
    ushort4 o;
    o.x = f2bf(Ws[cc][rr]);     o.y = f2bf(Ws[cc + 1][rr]);
    o.z = f2bf(Ws[cc + 2][rr]); o.w = f2bf(Ws[cc + 3][rr]);
    *(ushort4*)&out[(size_t)(n0 + rr) * K + k0 + cc] = o;
  }
}

// ---- transpose bf16: [BH][T][128] -> [BH][128][T] (plain layout) ----
__global__ void transp_v(const uint16_t* __restrict__ in, uint16_t* __restrict__ out, int T) {
  __shared__ uint16_t Vsm[64][72];
  const int t0 = blockIdx.x * 64, d0 = blockIdx.y * 64, bh = blockIdx.z;
  const uint16_t* ip = in + (size_t)bh * T * 128;
  uint16_t* op = out + (size_t)bh * 128 * T;
  const int t = threadIdx.x;
  const int r = t >> 3, c = (t & 7) << 3;
#pragma unroll
  for (int it = 0; it < 2; ++it) {
    u16x8 v = *(const u16x8*)&ip[(size_t)(t0 + it * 32 + r) * 128 + d0 + c];
#pragma unroll
    for (int j = 0; j < 8; ++j) Vsm[it * 32 + r][c + j] = v[j];
  }
  __syncthreads();
#pragma unroll
  for (int it = 0; it < 2; ++it) {
    const int rr = it * 32 + r;  // d index in tile
    const int cc = c;            // t index in tile
    u16x8 o;
#pragma unroll
    for (int j = 0; j < 8; ++j) o[j] = Vsm[cc + j][rr];
    *(u16x8*)&op[(size_t)(d0 + rr) * T + t0 + cc] = o;
  }
}

// ------------- GEMM: C[M][N] = A[M][K] * Bt[N][K]^T + bias -------------
// EPI==0: scatter bf16 into q (scaled by QSC) / k / v layouts (plain).
// EPI==1: f32 out[M][N].
template <int EPI>
__global__ __launch_bounds__(256, 2)
void gemm_bt(const uint16_t* __restrict__ A, const uint16_t* __restrict__ Bt,
             const float* __restrict__ bias, float* __restrict__ outF,
             uint16_t* __restrict__ q, uint16_t* __restrict__ kk, uint16_t* __restrict__ v,
             int M, int N, int K) {
  constexpr int BK = 32;
  __shared__ uint16_t As[128 * BK];
  __shared__ uint16_t Bs[128 * BK];
  // bijective XCD swizzle (grid sizes here are multiples of 8)
  int bid = (int)blockIdx.x;
  const int q8 = (int)gridDim.x >> 3;
  bid = (bid & 7) * q8 + (bid >> 3);
  const int nbn = N >> 7;
  const int brow = (bid / nbn) << 7;
  const int bcol = (bid % nbn) << 7;
  const int t = threadIdx.x;
  const int w = t >> 6, lane = t & 63;
  const int wr = ((w >> 1) << 6), wc = ((w & 1) << 6);
  const int lr = lane & 15, lk = (lane >> 4) << 3;
  const int sr = t >> 2;
  const int sc = (t & 3) << 3;

  f32x4 acc[4][4];
#pragma unroll
  for (int i = 0; i < 4; ++i)
#pragma unroll
    for (int j = 0; j < 4; ++j) acc[i][j] = f32x4{0.f, 0.f, 0.f, 0.f};

  const uint16_t* Ap = A + (size_t)(brow + sr) * K + sc;
  const uint16_t* Bp = Bt + (size_t)(bcol + sr) * K + sc;
  const size_t rowskip = (size_t)64 * K;

  for (int k0 = 0; k0 < K; k0 += BK) {
    async16(&As[sr * BK + sc], Ap + k0);
    async16(&As[(64 + sr) * BK + sc], Ap + rowskip + k0);
    async16(&Bs[sr * BK + sc], Bp + k0);
    async16(&Bs[(64 + sr) * BK + sc], Bp + rowskip + k0);
    __syncthreads();
    u16x8 af[4], bf[4];
#pragma unroll
    for (int i = 0; i < 4; ++i) af[i] = *(const u16x8*)&As[(wr + i * 16 + lr) * BK + lk];
#pragma unroll
    for (int j = 0; j < 4; ++j) bf[j] = *(const u16x8*)&Bs[(wc + j * 16 + lr) * BK + lk];
#pragma unroll
    for (int i = 0; i < 4; ++i)
#pragma unroll
      for (int j = 0; j < 4; ++j) acc[i][j] = mfma16(af[i], bf[j], acc[i][j]);
    __syncthreads();
  }

#pragma unroll
  for (int i = 0; i < 4; ++i) {
#pragma unroll
    for (int j = 0; j < 4; ++j) {
      const int col = bcol + wc + j * 16 + lr;
      const float bb = bias[col];
#pragma unroll
      for (int r = 0; r < 4; ++r) {
        const int row = brow + wr + i * 16 + ((lane >> 4) << 2) + r;
        const float val = acc[i][j][r] + bb;
        if (EPI == 1) {
          outF[(size_t)row * N + col] = val;
        } else {
          const int b_ = row >> 11, tt = row & 2047;
          const int d = col & 127;
          if (col < 2048) {
            const int hh = col >> 7;
            q[((size_t)((b_ * 16 + hh) * 2048 + tt) << 7) + d] = f2bf(val * QSC);
          } else if (col < 2560) {
            const int hh = (col - 2048) >> 7;
            kk[((size_t)((b_ * 4 + hh) * 2048 + tt) << 7) + d] = f2bf(val);
          } else {
            const int hh = (col - 2560) >> 7;
            v[((size_t)((b_ * 4 + hh) * 2048 + tt) << 7) + d] = f2bf(val);
          }
        }
      }
    }
  }
}

// ------------- flash attention (causal, GQA 4:1), 32x32 MFMA + in-reg P -----
// Diagonal pairing: grid (8,16,4); block pr does qb=15-pr then qb=pr (34 tiles
// each). LDS = K dbuf 32K + V dbuf 32K = 64 KB (Ps ELIMINATED) -> 2 blocks/CU
// co-resident (round 7: 80KB fit only 1 -> 48% idle).
// QK^T: S^T = mfma32(K_frag, Q_frag) twice (k=0..63). Lane owns q-row lane&31;
// scores at k=32m+(reg&3)+8(reg>>2)+4b5. Softmax: 31 fmax + 1 shfl_xor(32).
// P->PV: B-operand needs P[k=8*b5+j][q]; redistribution is purely across
// lane bit5 + a b5-dependent register pick -> 16 cvt_pk + 8 shfl_xor + selects.
__global__ __launch_bounds__(256, 1)
void attn_fwd(const uint16_t* __restrict__ Q,   // [B*16][T][128], pre-scaled by QSC
              const uint16_t* __restrict__ Kg,  // [B*4][T][128]
              const uint16_t* __restrict__ Vt,  // [B*4][128][T]
              uint16_t* __restrict__ Y,         // [B*T][2048], col offset h*128
              int T) {
  __shared__ __align__(16) uint16_t Ks[2][64 * 128];   // 32 KB
  __shared__ __align__(16) uint16_t Vs[2][128 * 64];   // 32 KB
  const int pr = blockIdx.x;                  // 0..7
  const int h = blockIdx.y, b = blockIdx.z;
  const int hkv = h >> 2;

  const int t = threadIdx.x, w = t >> 6, lane = t & 63;
  const int ql = lane & 31, b5 = lane >> 5;
  const int swz = (ql & 7) << 3;

  const uint16_t* Qh = Q + (size_t)(b * 16 + h) * T * 128;
  const uint16_t* Kp = Kg + (size_t)(b * 4 + hkv) * T * 128;
  const uint16_t* Vp = Vt + (size_t)(b * 4 + hkv) * 128 * T;

  // staging (round-7 verified): linear LDS dest, inverse-swizzled global src.
  auto stage = [&](int buf, int kv0) {
#pragma unroll
    for (int it = 0; it < 4; ++it) {
      const int krow = w * 16 + it * 4 + (lane >> 4);
      const int kcol = ((lane & 15) << 3) ^ ((krow & 7) << 3);
      async16(&Ks[buf][((w * 16 + it * 4) << 7) + (lane << 3)],
              &Kp[(size_t)(kv0 + krow) * 128 + kcol]);
    }
#pragma unroll
    for (int it = 0; it < 4; ++it) {
      const int vrow = w * 32 + it * 8 + (lane >> 3);
      const int vcol = ((lane & 7) << 3) ^ ((vrow & 7) << 3);
      async16(&Vs[buf][((w * 32 + it * 8) << 6) + (lane << 3)],
              &Vp[(size_t)vrow * T + kv0 + vcol]);
    }
  };

  for (int half = 0; half < 2; ++half) {
    const int qb = half == 0 ? 15 - pr : pr;
    const uint16_t* Qp = Qh + (size_t)(qb * 128) * 128;
    const int row0 = qb * 128 + w * 32;
    const int qrow = row0 + ql;

    // Q fragments (B-operand of 32x32x16): lane holds Q[q=ql][kc*16+b5*8+j]
    u16x8 qf[8];
#pragma unroll
    for (int kc = 0; kc < 8; ++kc)
      qf[kc] = *(const u16x8*)&Qp[(size_t)(w * 32 + ql) * 128 + kc * 16 + b5 * 8];

    f32x16 o[4];  // O^T: lane holds O[d=32db+(reg&3)+8(reg>>2)+4b5][q=ql]
#pragma unroll
    for (int db = 0; db < 4; ++db)
#pragma unroll
      for (int r = 0; r < 16; ++r) o[db][r] = 0.f;
    float mrow = -3e38f, lrow = 0.f;

    const int ntiles = 2 * qb + 2;
    const int myn = 2 * qb + 1 + (w >> 1);  // waves 0,1 skip last (fully-masked)

    stage(0, 0);
    __syncthreads();

    int cur = 0;
    for (int tile = 0; tile < ntiles; ++tile) {
      if (tile + 1 < ntiles) stage(cur ^ 1, (tile + 1) << 6);

      if (tile < myn) {
        const int kv0 = tile << 6;
        f32x16 s[2];
#pragma unroll
        for (int m = 0; m < 2; ++m)
#pragma unroll
          for (int r = 0; r < 16; ++r) s[m][r] = 0.f;
        __builtin_amdgcn_s_setprio(1);
#pragma unroll
        for (int kc = 0; kc < 8; ++kc) {
          const int cc = (kc * 16 + b5 * 8) ^ swz;
          u16x8 k0f = *(const u16x8*)&Ks[cur][ql * 128 + cc];
          u16x8 k1f = *(const u16x8*)&Ks[cur][(32 + ql) * 128 + cc];
          s[0] = mfma32(k0f, qf[kc], s[0]);
          s[1] = mfma32(k1f, qf[kc], s[1]);
        }
        __builtin_amdgcn_s_setprio(0);

        // causal mask
        if (kv0 + 63 > row0) {
#pragma unroll
          for (int m = 0; m < 2; ++m)
#pragma unroll
            for (int r = 0; r < 16; ++r) {
              const int kg = kv0 + 32 * m + (r & 3) + 8 * (r >> 2) + 4 * b5;
              if (kg > qrow) s[m][r] = -3e38f;
            }
        }
        // online softmax (lane-local row; 1 cross-lane hop)
        float mx = s[0][0];
#pragma unroll
        for (int m = 0; m < 2; ++m)
#pragma unroll
          for (int r = 0; r < 16; ++r) mx = fmaxf(mx, s[m][r]);
        mx = fmaxf(mx, __shfl_xor(mx, 32));
        const float mnew = fmaxf(mrow, mx);
        const float sc = exp2f(mrow - mnew);
        float ps = 0.f;
#pragma unroll
        for (int m = 0; m < 2; ++m)
#pragma unroll
          for (int r = 0; r < 16; ++r) {
            s[m][r] = exp2f(s[m][r] - mnew);
            ps += s[m][r];
          }
        ps += __shfl_xor(ps, 32);
        mrow = mnew;
        lrow = lrow * sc + ps;
        // T13: skip O-rescale when max stable across the whole wave
        if (!__all(sc == 1.f)) {
#pragma unroll
          for (int db = 0; db < 4; ++db)
#pragma unroll
            for (int r = 0; r < 16; ++r) o[db][r] *= sc;
        }

        // P -> B-operand fragments, fully in-register (cross-b5 exchange only)
        u16x8 pa[4];
#pragma unroll
        for (int m = 0; m < 2; ++m) {
          uint32_t pw[4][2];
#pragma unroll
          for (int a = 0; a < 4; ++a)
#pragma unroll
            for (int hh = 0; hh < 2; ++hh)
              pw[a][hh] = (uint32_t)f2bfn(s[m][4 * a + 2 * hh]) |
                          ((uint32_t)f2bfn(s[m][4 * a + 2 * hh + 1]) << 16);
#pragma unroll
          for (int c = 0; c < 2; ++c) {
            uint32_t wd[4];
#pragma unroll
            for (int hh = 0; hh < 2; ++hh) {
              const uint32_t mine  = b5 ? pw[2 * c + 1][hh] : pw[2 * c][hh];
              const uint32_t yours = b5 ? pw[2 * c][hh] : pw[2 * c + 1][hh];
              const uint32_t x = (uint32_t)__shfl_xor((int)yours, 32);
              wd[hh] = b5 ? x : mine;
              wd[2 + hh] = b5 ? mine : x;
            }
            u32x4 tmp = {wd[0], wd[1], wd[2], wd[3]};
            pa[2 * m + c] = __builtin_bit_cast(u16x8, tmp);
          }
        }

        __builtin_amdgcn_s_setprio(1);
#pragma unroll
        for (int db = 0; db < 4; ++db) {
#pragma unroll
          for (int kf = 0; kf < 4; ++kf) {
            u16x8 vf = *(const u16x8*)&Vs[cur][(32 * db + ql) * 64 +
                                              ((kf * 16 + b5 * 8) ^ swz)];
            o[db] = mfma32(vf, pa[kf], o[db]);
          }
        }
        __builtin_amdgcn_s_setprio(0);
      }
      __syncthreads();  // drains this tile's prefetch, syncs buffer reuse
      cur ^= 1;
    }

    uint16_t* Yp = Y + ((size_t)(b * T + row0 + ql)) * 2048 + h * 128 + b5 * 4;
    const float inv = 1.f / lrow;
#pragma unroll
    for (int db = 0; db < 4; ++db)
#pragma unroll
      for (int a = 0; a < 4; ++a) {
        u16x4v pk;
#pragma unroll
        for (int r = 0; r < 4; ++r) pk[r] = f2bfn(o[db][4 * a + r] * inv);
        *(u16x4v*)&Yp[db * 32 + a * 8] = pk;
      }
  }
}

extern "C" void kernel_launch(void* const* d_in, const int* in_sizes, int n_in,
                              void* d_out, int out_size, void* d_ws, size_t ws_size,
                              hipStream_t stream) {
  const float* x      = (const float*)d_in[0];
  const float* W_attn = (const float*)d_in[1];
  const float* b_attn = (const float*)d_in[2];
  const float* W_proj = (const float*)d_in[3];
  const float* b_proj = (const float*)d_in[4];
  float* out = (float*)d_out;

  const int B = 4, T = 2048, C = 2048, H = 16, HKV = 4, HS = 128;
  const int M = B * T;               // 8192
  const int Nqkv = C + 2 * HKV * HS; // 3072

  uint8_t* ws = (uint8_t*)d_ws;
  size_t off = 0;
  auto alloc = [&](size_t bytes) {
    void* p = ws + off;
    off += (bytes + 255) & ~(size_t)255;
    return p;
  };
  uint16_t* xb  = (uint16_t*)alloc((size_t)M * C * 2);      // reused as yb after qkv
  uint16_t* WaT = (uint16_t*)alloc((size_t)Nqkv * C * 2);
  uint16_t* WpT = (uint16_t*)alloc((size_t)C * C * 2);
  uint16_t* qb  = (uint16_t*)alloc((size_t)B * H * T * HS * 2);
  uint16_t* kb  = (uint16_t*)alloc((size_t)B * HKV * T * HS * 2);
  uint16_t* vb  = (uint16_t*)alloc((size_t)B * HKV * T * HS * 2);
  uint16_t* vtb = (uint16_t*)alloc((size_t)B * HKV * HS * T * 2);
  uint16_t* yb  = xb;

  cvt_f32_bf16<<<2048, 256, 0, stream>>>(x, xb, M * C / 4);
  transp_cvt<<<dim3(Nqkv / 64, C / 64), 256, 0, stream>>>(W_attn, WaT, C, Nqkv);
  transp_cvt<<<dim3(C / 64, C / 64), 256, 0, stream>>>(W_proj, WpT, C, C);
  gemm_bt<0><<<dim3((M / 128) * (Nqkv / 128)), 256, 0, stream>>>(
      xb, WaT, b_attn, nullptr, qb, kb, vb, M, Nqkv, C);
  transp_v<<<dim3(T / 64, 2, B * HKV), 256, 0, stream>>>(vb, vtb, T);
  attn_fwd<<<dim3(8, H, B), 256, 0, stream>>>(qb, kb, vtb, yb, T);
  gemm_bt<1><<<dim3((M / 128) * (C / 128)), 256, 0, stream>>>(
      yb, WpT, b_proj, out, nullptr, nullptr, nullptr, M, C, C);
}

// Round 9
// 378.787 us; speedup vs baseline: 1.5476x; 1.1546x over previous
//
#include <hip/hip_runtime.h>
#include <stdint.h>

#define DEVI __device__ __forceinline__

typedef __attribute__((ext_vector_type(8))) uint16_t u16x8;
typedef __attribute__((ext_vector_type(4))) uint16_t u16x4v;
typedef __attribute__((ext_vector_type(4))) uint32_t u32x4;
typedef __attribute__((ext_vector_type(8))) __bf16 bf16x8;
typedef __attribute__((ext_vector_type(4))) float f32x4;
typedef __attribute__((ext_vector_type(16))) float f32x16;

DEVI uint16_t f2bf(float x) {
  union { float f; uint32_t u; } v; v.f = x;
  return (uint16_t)((v.u + 0x7fffu + ((v.u >> 16) & 1u)) >> 16);
}

DEVI uint16_t f2bfn(float f) {
  __bf16 h = (__bf16)f;
  return __builtin_bit_cast(uint16_t, h);
}

DEVI f32x4 mfma16(u16x8 a, u16x8 b, f32x4 c) {
  return __builtin_amdgcn_mfma_f32_16x16x32_bf16(
      __builtin_bit_cast(bf16x8, a), __builtin_bit_cast(bf16x8, b), c, 0, 0, 0);
}

DEVI f32x16 mfma32(u16x8 a, u16x8 b, f32x16 c) {
  return __builtin_amdgcn_mfma_f32_32x32x16_bf16(
      __builtin_bit_cast(bf16x8, a), __builtin_bit_cast(bf16x8, b), c, 0, 0, 0);
}

DEVI void async16(void* lds, const void* g) {
  __builtin_amdgcn_global_load_lds(
      (const __attribute__((address_space(1))) uint32_t*)g,
      (__attribute__((address_space(3))) uint32_t*)lds, 16, 0, 0);
}

// 1/sqrt(128) * log2(e): softmax computed in exp2 domain, scale folded into Q.
#define QSC 0.12751742925f

// ---------------- elementwise f32 -> bf16 ----------------
__global__ void cvt_f32_bf16(const float* __restrict__ in, uint16_t* __restrict__ out, int n4) {
  int i = blockIdx.x * blockDim.x + threadIdx.x;
  const int st = gridDim.x * blockDim.x;
  for (; i < n4; i += st) {
    float4 v = ((const float4*)in)[i];
    u16x4v o;
    o[0] = f2bf(v.x); o[1] = f2bf(v.y); o[2] = f2bf(v.z); o[3] = f2bf(v.w);
    ((u16x4v*)out)[i] = o;
  }
}

// ------------- transpose + convert: f32 [K][N] -> bf16 [N][K] -------------
__global__ void transp_cvt(const float* __restrict__ in, uint16_t* __restrict__ out,
                           int K, int N) {
  __shared__ float Ws[64][65];
  const int n0 = blockIdx.x * 64, k0 = blockIdx.y * 64;
  const int t = threadIdx.x;
  const int r = t >> 4, c = (t & 15) << 2;
#pragma unroll
  for (int it = 0; it < 4; ++it) {
    float4 v = *(const float4*)&in[(size_t)(k0 + it * 16 + r) * N + n0 + c];
    Ws[it * 16 + r][c] = v.x; Ws[it * 16 + r][c + 1] = v.y;
    Ws[it * 16 + r][c + 2] = v.z; Ws[it * 16 + r][c + 3] = v.w;
  }
  __syncthreads();
#pragma unroll
  for (int it = 0; it < 4; ++it) {
    const int rr = it * 16 + r;   // n index in tile
    const int cc = c;             // k index in tile
    ushort4 o;
    o.x = f2bf(Ws[cc][rr]);     o.y = f2bf(Ws[cc + 1][rr]);
    o.z = f2bf(Ws[cc + 2][rr]); o.w = f2bf(Ws[cc + 3][rr]);
    *(ushort4*)&out[(size_t)(n0 + rr) * K + k0 + cc] = o;
  }
}

// ---- transpose bf16: [BH][T][128] -> [BH][128][T] (plain layout) ----
__global__ void transp_v(const uint16_t* __restrict__ in, uint16_t* __restrict__ out, int T) {
  __shared__ uint16_t Vsm[64][72];
  const int t0 = blockIdx.x * 64, d0 = blockIdx.y * 64, bh = blockIdx.z;
  const uint16_t* ip = in + (size_t)bh * T * 128;
  uint16_t* op = out + (size_t)bh * 128 * T;
  const int t = threadIdx.x;
  const int r = t >> 3, c = (t & 7) << 3;
#pragma unroll
  for (int it = 0; it < 2; ++it) {
    u16x8 v = *(const u16x8*)&ip[(size_t)(t0 + it * 32 + r) * 128 + d0 + c];
#pragma unroll
    for (int j = 0; j < 8; ++j) Vsm[it * 32 + r][c + j] = v[j];
  }
  __syncthreads();
#pragma unroll
  for (int it = 0; it < 2; ++it) {
    const int rr = it * 32 + r;  // d index in tile
    const int cc = c;            // t index in tile
    u16x8 o;
#pragma unroll
    for (int j = 0; j < 8; ++j) o[j] = Vsm[cc + j][rr];
    *(u16x8*)&op[(size_t)(d0 + rr) * T + t0 + cc] = o;
  }
}

// ------------- GEMM: C[M][N] = A[M][K] * Bt[N][K]^T + bias -------------
// EPI==0: scatter bf16 into q (scaled by QSC) / k / v layouts (plain).
// EPI==1: f32 out[M][N].
template <int EPI>
__global__ __launch_bounds__(256, 2)
void gemm_bt(const uint16_t* __restrict__ A, const uint16_t* __restrict__ Bt,
             const float* __restrict__ bias, float* __restrict__ outF,
             uint16_t* __restrict__ q, uint16_t* __restrict__ kk, uint16_t* __restrict__ v,
             int M, int N, int K) {
  constexpr int BK = 32;
  __shared__ uint16_t As[128 * BK];
  __shared__ uint16_t Bs[128 * BK];
  // bijective XCD swizzle (grid sizes here are multiples of 8)
  int bid = (int)blockIdx.x;
  const int q8 = (int)gridDim.x >> 3;
  bid = (bid & 7) * q8 + (bid >> 3);
  const int nbn = N >> 7;
  const int brow = (bid / nbn) << 7;
  const int bcol = (bid % nbn) << 7;
  const int t = threadIdx.x;
  const int w = t >> 6, lane = t & 63;
  const int wr = ((w >> 1) << 6), wc = ((w & 1) << 6);
  const int lr = lane & 15, lk = (lane >> 4) << 3;
  const int sr = t >> 2;
  const int sc = (t & 3) << 3;

  f32x4 acc[4][4];
#pragma unroll
  for (int i = 0; i < 4; ++i)
#pragma unroll
    for (int j = 0; j < 4; ++j) acc[i][j] = f32x4{0.f, 0.f, 0.f, 0.f};

  const uint16_t* Ap = A + (size_t)(brow + sr) * K + sc;
  const uint16_t* Bp = Bt + (size_t)(bcol + sr) * K + sc;
  const size_t rowskip = (size_t)64 * K;

  for (int k0 = 0; k0 < K; k0 += BK) {
    async16(&As[sr * BK + sc], Ap + k0);
    async16(&As[(64 + sr) * BK + sc], Ap + rowskip + k0);
    async16(&Bs[sr * BK + sc], Bp + k0);
    async16(&Bs[(64 + sr) * BK + sc], Bp + rowskip + k0);
    __syncthreads();
    u16x8 af[4], bf[4];
#pragma unroll
    for (int i = 0; i < 4; ++i) af[i] = *(const u16x8*)&As[(wr + i * 16 + lr) * BK + lk];
#pragma unroll
    for (int j = 0; j < 4; ++j) bf[j] = *(const u16x8*)&Bs[(wc + j * 16 + lr) * BK + lk];
#pragma unroll
    for (int i = 0; i < 4; ++i)
#pragma unroll
      for (int j = 0; j < 4; ++j) acc[i][j] = mfma16(af[i], bf[j], acc[i][j]);
    __syncthreads();
  }

#pragma unroll
  for (int i = 0; i < 4; ++i) {
#pragma unroll
    for (int j = 0; j < 4; ++j) {
      const int col = bcol + wc + j * 16 + lr;
      const float bb = bias[col];
#pragma unroll
      for (int r = 0; r < 4; ++r) {
        const int row = brow + wr + i * 16 + ((lane >> 4) << 2) + r;
        const float val = acc[i][j][r] + bb;
        if (EPI == 1) {
          outF[(size_t)row * N + col] = val;
        } else {
          const int b_ = row >> 11, tt = row & 2047;
          const int d = col & 127;
          if (col < 2048) {
            const int hh = col >> 7;
            q[((size_t)((b_ * 16 + hh) * 2048 + tt) << 7) + d] = f2bf(val * QSC);
          } else if (col < 2560) {
            const int hh = (col - 2048) >> 7;
            kk[((size_t)((b_ * 4 + hh) * 2048 + tt) << 7) + d] = f2bf(val);
          } else {
            const int hh = (col - 2560) >> 7;
            v[((size_t)((b_ * 4 + hh) * 2048 + tt) << 7) + d] = f2bf(val);
          }
        }
      }
    }
  }
}

// ------------- flash attention (causal, GQA 4:1), 512-thread blocks -------
// 8 waves x 32 q-rows = 256-row Q super-block; one staged K/V tile feeds all
// 8 waves (stage bytes per q-row halved vs round 8). Diagonal pairing: grid
// (4,16,4); block pr does qb=7-pr then qb=pr -> uniform 36 tiles. 256 blocks
// = exactly 1/CU; 8 waves/CU = 2/SIMD guaranteed -> cross-wave latency hiding
// (rounds 7-8 ran 1 wave/SIMD; ~70% of tile wall was exposed latency).
// Inside: 32x32 MFMA, in-reg P (cross-b5 shfl only), K/V dbuf via
// global_load_lds(16B) w/ rule-#21 swizzle, T13 rescale skip, setprio.
__global__ __launch_bounds__(512, 1)
void attn_fwd(const uint16_t* __restrict__ Q,   // [B*16][T][128], pre-scaled by QSC
              const uint16_t* __restrict__ Kg,  // [B*4][T][128]
              const uint16_t* __restrict__ Vt,  // [B*4][128][T]
              uint16_t* __restrict__ Y,         // [B*T][2048], col offset h*128
              int T) {
  __shared__ __align__(16) uint16_t Ks[2][64 * 128];   // 32 KB
  __shared__ __align__(16) uint16_t Vs[2][128 * 64];   // 32 KB
  const int pr = blockIdx.x;                  // 0..3
  const int h = blockIdx.y, b = blockIdx.z;
  const int hkv = h >> 2;

  const int t = threadIdx.x, w = t >> 6, lane = t & 63;
  const int ql = lane & 31, b5 = lane >> 5;
  const int swz = (ql & 7) << 3;

  const uint16_t* Qh = Q + (size_t)(b * 16 + h) * T * 128;
  const uint16_t* Kp = Kg + (size_t)(b * 4 + hkv) * T * 128;
  const uint16_t* Vp = Vt + (size_t)(b * 4 + hkv) * 128 * T;

  // staging with 512 threads: 2 K insts + 2 V insts per thread per tile.
  // Linear LDS dest (wave base + lane*16B), inverse-swizzled global source.
  auto stage = [&](int buf, int kv0) {
#pragma unroll
    for (int it = 0; it < 2; ++it) {
      const int krow = it * 32 + w * 4 + (lane >> 4);         // 0..63
      const int kcol = ((lane & 15) << 3) ^ ((krow & 7) << 3);
      async16(&Ks[buf][(it * 32 + w * 4) * 128 + lane * 8],
              &Kp[(size_t)(kv0 + krow) * 128 + kcol]);
    }
#pragma unroll
    for (int it = 0; it < 2; ++it) {
      const int vrow = it * 64 + w * 8 + (lane >> 3);         // 0..127
      const int vcol = ((lane & 7) << 3) ^ ((vrow & 7) << 3);
      async16(&Vs[buf][(it * 64 + w * 8) * 64 + lane * 8],
              &Vp[(size_t)vrow * T + kv0 + vcol]);
    }
  };

  for (int half = 0; half < 2; ++half) {
    const int qb = half == 0 ? 7 - pr : pr;                   // 256-row blocks
    const uint16_t* Qp = Qh + (size_t)(qb * 256) * 128;
    const int row0 = qb * 256 + w * 32;
    const int qrow = row0 + ql;

    // Q fragments (B-operand of 32x32x16): lane holds Q[q=ql][kc*16+b5*8+j]
    u16x8 qf[8];
#pragma unroll
    for (int kc = 0; kc < 8; ++kc)
      qf[kc] = *(const u16x8*)&Qp[(size_t)(w * 32 + ql) * 128 + kc * 16 + b5 * 8];

    f32x16 o[4];  // O^T: lane holds O[d=32db+(reg&3)+8(reg>>2)+4b5][q=ql]
#pragma unroll
    for (int db = 0; db < 4; ++db)
#pragma unroll
      for (int r = 0; r < 16; ++r) o[db][r] = 0.f;
    float mrow = -3e38f, lrow = 0.f;

    const int ntiles = 4 * qb + 4;
    const int myn = 4 * qb + (w >> 1) + 1;  // waves skip fully-masked tail tiles

    stage(0, 0);
    __syncthreads();

    int cur = 0;
    for (int tile = 0; tile < ntiles; ++tile) {
      if (tile + 1 < ntiles) stage(cur ^ 1, (tile + 1) << 6);

      if (tile < myn) {
        const int kv0 = tile << 6;
        f32x16 s[2];
#pragma unroll
        for (int m = 0; m < 2; ++m)
#pragma unroll
          for (int r = 0; r < 16; ++r) s[m][r] = 0.f;
        __builtin_amdgcn_s_setprio(1);
#pragma unroll
        for (int kc = 0; kc < 8; ++kc) {
          const int cc = (kc * 16 + b5 * 8) ^ swz;
          u16x8 k0f = *(const u16x8*)&Ks[cur][ql * 128 + cc];
          u16x8 k1f = *(const u16x8*)&Ks[cur][(32 + ql) * 128 + cc];
          s[0] = mfma32(k0f, qf[kc], s[0]);
          s[1] = mfma32(k1f, qf[kc], s[1]);
        }
        __builtin_amdgcn_s_setprio(0);

        // causal mask
        if (kv0 + 63 > row0) {
#pragma unroll
          for (int m = 0; m < 2; ++m)
#pragma unroll
            for (int r = 0; r < 16; ++r) {
              const int kg = kv0 + 32 * m + (r & 3) + 8 * (r >> 2) + 4 * b5;
              if (kg > qrow) s[m][r] = -3e38f;
            }
        }
        // online softmax (lane-local row; 1 cross-lane hop)
        float mx = s[0][0];
#pragma unroll
        for (int m = 0; m < 2; ++m)
#pragma unroll
          for (int r = 0; r < 16; ++r) mx = fmaxf(mx, s[m][r]);
        mx = fmaxf(mx, __shfl_xor(mx, 32));
        const float mnew = fmaxf(mrow, mx);
        const float sc = exp2f(mrow - mnew);
        float ps = 0.f;
#pragma unroll
        for (int m = 0; m < 2; ++m)
#pragma unroll
          for (int r = 0; r < 16; ++r) {
            s[m][r] = exp2f(s[m][r] - mnew);
            ps += s[m][r];
          }
        ps += __shfl_xor(ps, 32);
        mrow = mnew;
        lrow = lrow * sc + ps;
        // T13: skip O-rescale when max stable across the whole wave
        if (!__all(sc == 1.f)) {
#pragma unroll
          for (int db = 0; db < 4; ++db)
#pragma unroll
            for (int r = 0; r < 16; ++r) o[db][r] *= sc;
        }

        // P -> B-operand fragments, fully in-register (cross-b5 exchange only)
        u16x8 pa[4];
#pragma unroll
        for (int m = 0; m < 2; ++m) {
          uint32_t pw[4][2];
#pragma unroll
          for (int a = 0; a < 4; ++a)
#pragma unroll
            for (int hh = 0; hh < 2; ++hh)
              pw[a][hh] = (uint32_t)f2bfn(s[m][4 * a + 2 * hh]) |
                          ((uint32_t)f2bfn(s[m][4 * a + 2 * hh + 1]) << 16);
#pragma unroll
          for (int c = 0; c < 2; ++c) {
            uint32_t wd[4];
#pragma unroll
            for (int hh = 0; hh < 2; ++hh) {
              const uint32_t mine  = b5 ? pw[2 * c + 1][hh] : pw[2 * c][hh];
              const uint32_t yours = b5 ? pw[2 * c][hh] : pw[2 * c + 1][hh];
              const uint32_t x = (uint32_t)__shfl_xor((int)yours, 32);
              wd[hh] = b5 ? x : mine;
              wd[2 + hh] = b5 ? mine : x;
            }
            u32x4 tmp = {wd[0], wd[1], wd[2], wd[3]};
            pa[2 * m + c] = __builtin_bit_cast(u16x8, tmp);
          }
        }

        __builtin_amdgcn_s_setprio(1);
#pragma unroll
        for (int db = 0; db < 4; ++db) {
#pragma unroll
          for (int kf = 0; kf < 4; ++kf) {
            u16x8 vf = *(const u16x8*)&Vs[cur][(32 * db + ql) * 64 +
                                              ((kf * 16 + b5 * 8) ^ swz)];
            o[db] = mfma32(vf, pa[kf], o[db]);
          }
        }
        __builtin_amdgcn_s_setprio(0);
      }
      __syncthreads();  // drains this tile's prefetch, syncs buffer reuse
      cur ^= 1;
    }

    uint16_t* Yp = Y + ((size_t)(b * T + row0 + ql)) * 2048 + h * 128 + b5 * 4;
    const float inv = 1.f / lrow;
#pragma unroll
    for (int db = 0; db < 4; ++db)
#pragma unroll
      for (int a = 0; a < 4; ++a) {
        u16x4v pk;
#pragma unroll
        for (int r = 0; r < 4; ++r) pk[r] = f2bfn(o[db][4 * a + r] * inv);
        *(u16x4v*)&Yp[db * 32 + a * 8] = pk;
      }
  }
}

extern "C" void kernel_launch(void* const* d_in, const int* in_sizes, int n_in,
                              void* d_out, int out_size, void* d_ws, size_t ws_size,
                              hipStream_t stream) {
  const float* x      = (const float*)d_in[0];
  const float* W_attn = (const float*)d_in[1];
  const float* b_attn = (const float*)d_in[2];
  const float* W_proj = (const float*)d_in[3];
  const float* b_proj = (const float*)d_in[4];
  float* out = (float*)d_out;

  const int B = 4, T = 2048, C = 2048, H = 16, HKV = 4, HS = 128;
  const int M = B * T;               // 8192
  const int Nqkv = C + 2 * HKV * HS; // 3072

  uint8_t* ws = (uint8_t*)d_ws;
  size_t off = 0;
  auto alloc = [&](size_t bytes) {
    void* p = ws + off;
    off += (bytes + 255) & ~(size_t)255;
    return p;
  };
  uint16_t* xb  = (uint16_t*)alloc((size_t)M * C * 2);      // reused as yb after qkv
  uint16_t* WaT = (uint16_t*)alloc((size_t)Nqkv * C * 2);
  uint16_t* WpT = (uint16_t*)alloc((size_t)C * C * 2);
  uint16_t* qb  = (uint16_t*)alloc((size_t)B * H * T * HS * 2);
  uint16_t* kb  = (uint16_t*)alloc((size_t)B * HKV * T * HS * 2);
  uint16_t* vb  = (uint16_t*)alloc((size_t)B * HKV * T * HS * 2);
  uint16_t* vtb = (uint16_t*)alloc((size_t)B * HKV * HS * T * 2);
  uint16_t* yb  = xb;

  cvt_f32_bf16<<<2048, 256, 0, stream>>>(x, xb, M * C / 4);
  transp_cvt<<<dim3(Nqkv / 64, C / 64), 256, 0, stream>>>(W_attn, WaT, C, Nqkv);
  transp_cvt<<<dim3(C / 64, C / 64), 256, 0, stream>>>(W_proj, WpT, C, C);
  gemm_bt<0><<<dim3((M / 128) * (Nqkv / 128)), 256, 0, stream>>>(
      xb, WaT, b_attn, nullptr, qb, kb, vb, M, Nqkv, C);
  transp_v<<<dim3(T / 64, 2, B * HKV), 256, 0, stream>>>(vb, vtb, T);
  attn_fwd<<<dim3(4, H, B), 512, 0, stream>>>(qb, kb, vtb, yb, T);
  gemm_bt<1><<<dim3((M / 128) * (C / 128)), 256, 0, stream>>>(
      yb, WpT, b_proj, out, nullptr, nullptr, nullptr, M, C, C);
}

// Round 10
// 368.632 us; speedup vs baseline: 1.5902x; 1.0275x over previous
//
#include <hip/hip_runtime.h>
#include <stdint.h>

#define DEVI __device__ __forceinline__

typedef __attribute__((ext_vector_type(8))) uint16_t u16x8;
typedef __attribute__((ext_vector_type(4))) uint16_t u16x4v;
typedef __attribute__((ext_vector_type(4))) uint32_t u32x4;
typedef __attribute__((ext_vector_type(8))) __bf16 bf16x8;
typedef __attribute__((ext_vector_type(4))) float f32x4;
typedef __attribute__((ext_vector_type(16))) float f32x16;

DEVI uint16_t f2bf(float x) {
  union { float f; uint32_t u; } v; v.f = x;
  return (uint16_t)((v.u + 0x7fffu + ((v.u >> 16) & 1u)) >> 16);
}

DEVI uint16_t f2bfn(float f) {
  __bf16 h = (__bf16)f;
  return __builtin_bit_cast(uint16_t, h);
}

DEVI f32x4 mfma16(u16x8 a, u16x8 b, f32x4 c) {
  return __builtin_amdgcn_mfma_f32_16x16x32_bf16(
      __builtin_bit_cast(bf16x8, a), __builtin_bit_cast(bf16x8, b), c, 0, 0, 0);
}

DEVI f32x16 mfma32(u16x8 a, u16x8 b, f32x16 c) {
  return __builtin_amdgcn_mfma_f32_32x32x16_bf16(
      __builtin_bit_cast(bf16x8, a), __builtin_bit_cast(bf16x8, b), c, 0, 0, 0);
}

DEVI void async16(void* lds, const void* g) {
  __builtin_amdgcn_global_load_lds(
      (const __attribute__((address_space(1))) uint32_t*)g,
      (__attribute__((address_space(3))) uint32_t*)lds, 16, 0, 0);
}

// 1/sqrt(128) * log2(e): softmax computed in exp2 domain, scale folded into Q.
#define QSC 0.12751742925f

// ---------------- elementwise f32 -> bf16 ----------------
__global__ void cvt_f32_bf16(const float* __restrict__ in, uint16_t* __restrict__ out, int n4) {
  int i = blockIdx.x * blockDim.x + threadIdx.x;
  const int st = gridDim.x * blockDim.x;
  for (; i < n4; i += st) {
    float4 v = ((const float4*)in)[i];
    u16x4v o;
    o[0] = f2bf(v.x); o[1] = f2bf(v.y); o[2] = f2bf(v.z); o[3] = f2bf(v.w);
    ((u16x4v*)out)[i] = o;
  }
}

// ------------- transpose + convert: f32 [K][N] -> bf16 [N][K] -------------
__global__ void transp_cvt(const float* __restrict__ in, uint16_t* __restrict__ out,
                           int K, int N) {
  __shared__ float Ws[64][65];
  const int n0 = blockIdx.x * 64, k0 = blockIdx.y * 64;
  const int t = threadIdx.x;
  const int r = t >> 4, c = (t & 15) << 2;
#pragma unroll
  for (int it = 0; it < 4; ++it) {
    float4 v = *(const float4*)&in[(size_t)(k0 + it * 16 + r) * N + n0 + c];
    Ws[it * 16 + r][c] = v.x; Ws[it * 16 + r][c + 1] = v.y;
    Ws[it * 16 + r][c + 2] = v.z; Ws[it * 16 + r][c + 3] = v.w;
  }
  __syncthreads();
#pragma unroll
  for (int it = 0; it < 4; ++it) {
    const int rr = it * 16 + r;   // n index in tile
    const int cc = c;             // k index in tile
    ushort4 o;
    o.x = f2bf(Ws[cc][rr]);     o.y = f2bf(Ws[cc + 1][rr]);
    o.z = f2bf(Ws[cc + 2][rr]); o.w = f2bf(Ws[cc + 3][rr]);
    *(ushort4*)&out[(size_t)(n0 + rr) * K + k0 + cc] = o;
  }
}

// ---- transpose bf16: [BH][T][128] -> [BH][128][T] (plain layout) ----
__global__ void transp_v(const uint16_t* __restrict__ in, uint16_t* __restrict__ out, int T) {
  __shared__ uint16_t Vsm[64][72];
  const int t0 = blockIdx.x * 64, d0 = blockIdx.y * 64, bh = blockIdx.z;
  const uint16_t* ip = in + (size_t)bh * T * 128;
  uint16_t* op = out + (size_t)bh * 128 * T;
  const int t = threadIdx.x;
  const int r = t >> 3, c = (t & 7) << 3;
#pragma unroll
  for (int it = 0; it < 2; ++it) {
    u16x8 v = *(const u16x8*)&ip[(size_t)(t0 + it * 32 + r) * 128 + d0 + c];
#pragma unroll
    for (int j = 0; j < 8; ++j) Vsm[it * 32 + r][c + j] = v[j];
  }
  __syncthreads();
#pragma unroll
  for (int it = 0; it < 2; ++it) {
    const int rr = it * 32 + r;  // d index in tile
    const int cc = c;            // t index in tile
    u16x8 o;
#pragma unroll
    for (int j = 0; j < 8; ++j) o[j] = Vsm[cc + j][rr];
    *(u16x8*)&op[(size_t)(d0 + rr) * T + t0 + cc] = o;
  }
}

// ------------- GEMM: C[M][N] = A[M][K] * Bt[N][K]^T + bias -------------
// Round 10: (1) T2 chunk swizzle on As/Bs fragment reads — row r's logical
// 16B chunk c stored at physical chunk c^((r>>1)&3); glds dest stays linear,
// the GLOBAL source col is inverse-swizzled (rule #21), ds_read applies the
// same XOR. Kills the 8-way conflict (rows stride 64B -> 2 bank-quads).
// (2) double-buffered K-tiles: stage k+1 before compute(k), single barrier.
// EPI==0: scatter bf16 into q (scaled by QSC) / k / v layouts (plain).
// EPI==1: f32 out[M][N].
template <int EPI>
__global__ __launch_bounds__(256, 2)
void gemm_bt(const uint16_t* __restrict__ A, const uint16_t* __restrict__ Bt,
             const float* __restrict__ bias, float* __restrict__ outF,
             uint16_t* __restrict__ q, uint16_t* __restrict__ kk, uint16_t* __restrict__ v,
             int M, int N, int K) {
  constexpr int BK = 32;
  __shared__ uint16_t As[2][128 * BK];
  __shared__ uint16_t Bs[2][128 * BK];
  // bijective XCD swizzle (grid sizes here are multiples of 8)
  int bid = (int)blockIdx.x;
  const int q8 = (int)gridDim.x >> 3;
  bid = (bid & 7) * q8 + (bid >> 3);
  const int nbn = N >> 7;
  const int brow = (bid / nbn) << 7;
  const int bcol = (bid % nbn) << 7;
  const int t = threadIdx.x;
  const int w = t >> 6, lane = t & 63;
  const int wr = ((w >> 1) << 6), wc = ((w & 1) << 6);
  const int lr = lane & 15;
  // fragment read: logical chunk = lane>>4; physical = logical ^ ((row>>1)&3);
  // row = wr + i*16 + lr and (wr>>1)&3 == (i*16>>1)&3 == 0 -> s = (lr>>1)&3.
  const int pchunk = (((lane >> 4) ^ ((lr >> 1) & 3)) << 3);

  // staging: thread t owns rows sr, 64+sr (sr=t>>2), physical chunk t&3.
  // LDS dest linear in t (glds requirement); global source chunk inverse-
  // swizzled: (t&3)^((sr>>1)&3)  (same s for row 64+sr since 64 is even*4).
  const int sr = t >> 2;
  const int sdst = sr * BK + ((t & 3) << 3);
  const int scol = (((t & 3) ^ ((sr >> 1) & 3)) << 3);

  f32x4 acc[4][4];
#pragma unroll
  for (int i = 0; i < 4; ++i)
#pragma unroll
    for (int j = 0; j < 4; ++j) acc[i][j] = f32x4{0.f, 0.f, 0.f, 0.f};

  const uint16_t* Ap = A + (size_t)(brow + sr) * K + scol;
  const uint16_t* Bp = Bt + (size_t)(bcol + sr) * K + scol;
  const size_t rowskip = (size_t)64 * K;

  auto stage = [&](int buf, int k0) {
    async16(&As[buf][sdst], Ap + k0);
    async16(&As[buf][64 * BK + sdst], Ap + rowskip + k0);
    async16(&Bs[buf][sdst], Bp + k0);
    async16(&Bs[buf][64 * BK + sdst], Bp + rowskip + k0);
  };

  stage(0, 0);
  __syncthreads();  // vmcnt(0) drain emitted here by compiler

  int cur = 0;
  for (int k0 = 0; k0 < K; k0 += BK) {
    if (k0 + BK < K) stage(cur ^ 1, k0 + BK);  // prefetch flies under compute
    u16x8 af[4], bf[4];
#pragma unroll
    for (int i = 0; i < 4; ++i)
      af[i] = *(const u16x8*)&As[cur][(wr + i * 16 + lr) * BK + pchunk];
#pragma unroll
    for (int j = 0; j < 4; ++j)
      bf[j] = *(const u16x8*)&Bs[cur][(wc + j * 16 + lr) * BK + pchunk];
#pragma unroll
    for (int i = 0; i < 4; ++i)
#pragma unroll
      for (int j = 0; j < 4; ++j) acc[i][j] = mfma16(af[i], bf[j], acc[i][j]);
    __syncthreads();  // drains prefetch + syncs buffer reuse
    cur ^= 1;
  }

#pragma unroll
  for (int i = 0; i < 4; ++i) {
#pragma unroll
    for (int j = 0; j < 4; ++j) {
      const int col = bcol + wc + j * 16 + lr;
      const float bb = bias[col];
#pragma unroll
      for (int r = 0; r < 4; ++r) {
        const int row = brow + wr + i * 16 + ((lane >> 4) << 2) + r;
        const float val = acc[i][j][r] + bb;
        if (EPI == 1) {
          outF[(size_t)row * N + col] = val;
        } else {
          const int b_ = row >> 11, tt = row & 2047;
          const int d = col & 127;
          if (col < 2048) {
            const int hh = col >> 7;
            q[((size_t)((b_ * 16 + hh) * 2048 + tt) << 7) + d] = f2bf(val * QSC);
          } else if (col < 2560) {
            const int hh = (col - 2048) >> 7;
            kk[((size_t)((b_ * 4 + hh) * 2048 + tt) << 7) + d] = f2bf(val);
          } else {
            const int hh = (col - 2560) >> 7;
            v[((size_t)((b_ * 4 + hh) * 2048 + tt) << 7) + d] = f2bf(val);
          }
        }
      }
    }
  }
}

// ------------- flash attention (causal, GQA 4:1), 512-thread blocks -------
// (unchanged from round 9 — verified: attn no longer in top-5)
__global__ __launch_bounds__(512, 1)
void attn_fwd(const uint16_t* __restrict__ Q,   // [B*16][T][128], pre-scaled by QSC
              const uint16_t* __restrict__ Kg,  // [B*4][T][128]
              const uint16_t* __restrict__ Vt,  // [B*4][128][T]
              uint16_t* __restrict__ Y,         // [B*T][2048], col offset h*128
              int T) {
  __shared__ __align__(16) uint16_t Ks[2][64 * 128];   // 32 KB
  __shared__ __align__(16) uint16_t Vs[2][128 * 64];   // 32 KB
  const int pr = blockIdx.x;                  // 0..3
  const int h = blockIdx.y, b = blockIdx.z;
  const int hkv = h >> 2;

  const int t = threadIdx.x, w = t >> 6, lane = t & 63;
  const int ql = lane & 31, b5 = lane >> 5;
  const int swz = (ql & 7) << 3;

  const uint16_t* Qh = Q + (size_t)(b * 16 + h) * T * 128;
  const uint16_t* Kp = Kg + (size_t)(b * 4 + hkv) * T * 128;
  const uint16_t* Vp = Vt + (size_t)(b * 4 + hkv) * 128 * T;

  auto stage = [&](int buf, int kv0) {
#pragma unroll
    for (int it = 0; it < 2; ++it) {
      const int krow = it * 32 + w * 4 + (lane >> 4);         // 0..63
      const int kcol = ((lane & 15) << 3) ^ ((krow & 7) << 3);
      async16(&Ks[buf][(it * 32 + w * 4) * 128 + lane * 8],
              &Kp[(size_t)(kv0 + krow) * 128 + kcol]);
    }
#pragma unroll
    for (int it = 0; it < 2; ++it) {
      const int vrow = it * 64 + w * 8 + (lane >> 3);         // 0..127
      const int vcol = ((lane & 7) << 3) ^ ((vrow & 7) << 3);
      async16(&Vs[buf][(it * 64 + w * 8) * 64 + lane * 8],
              &Vp[(size_t)vrow * T + kv0 + vcol]);
    }
  };

  for (int half = 0; half < 2; ++half) {
    const int qb = half == 0 ? 7 - pr : pr;                   // 256-row blocks
    const uint16_t* Qp = Qh + (size_t)(qb * 256) * 128;
    const int row0 = qb * 256 + w * 32;
    const int qrow = row0 + ql;

    u16x8 qf[8];
#pragma unroll
    for (int kc = 0; kc < 8; ++kc)
      qf[kc] = *(const u16x8*)&Qp[(size_t)(w * 32 + ql) * 128 + kc * 16 + b5 * 8];

    f32x16 o[4];
#pragma unroll
    for (int db = 0; db < 4; ++db)
#pragma unroll
      for (int r = 0; r < 16; ++r) o[db][r] = 0.f;
    float mrow = -3e38f, lrow = 0.f;

    const int ntiles = 4 * qb + 4;
    const int myn = 4 * qb + (w >> 1) + 1;  // waves skip fully-masked tail tiles

    stage(0, 0);
    __syncthreads();

    int cur = 0;
    for (int tile = 0; tile < ntiles; ++tile) {
      if (tile + 1 < ntiles) stage(cur ^ 1, (tile + 1) << 6);

      if (tile < myn) {
        const int kv0 = tile << 6;
        f32x16 s[2];
#pragma unroll
        for (int m = 0; m < 2; ++m)
#pragma unroll
          for (int r = 0; r < 16; ++r) s[m][r] = 0.f;
        __builtin_amdgcn_s_setprio(1);
#pragma unroll
        for (int kc = 0; kc < 8; ++kc) {
          const int cc = (kc * 16 + b5 * 8) ^ swz;
          u16x8 k0f = *(const u16x8*)&Ks[cur][ql * 128 + cc];
          u16x8 k1f = *(const u16x8*)&Ks[cur][(32 + ql) * 128 + cc];
          s[0] = mfma32(k0f, qf[kc], s[0]);
          s[1] = mfma32(k1f, qf[kc], s[1]);
        }
        __builtin_amdgcn_s_setprio(0);

        if (kv0 + 63 > row0) {
#pragma unroll
          for (int m = 0; m < 2; ++m)
#pragma unroll
            for (int r = 0; r < 16; ++r) {
              const int kg = kv0 + 32 * m + (r & 3) + 8 * (r >> 2) + 4 * b5;
              if (kg > qrow) s[m][r] = -3e38f;
            }
        }
        float mx = s[0][0];
#pragma unroll
        for (int m = 0; m < 2; ++m)
#pragma unroll
          for (int r = 0; r < 16; ++r) mx = fmaxf(mx, s[m][r]);
        mx = fmaxf(mx, __shfl_xor(mx, 32));
        const float mnew = fmaxf(mrow, mx);
        const float sc = exp2f(mrow - mnew);
        float ps = 0.f;
#pragma unroll
        for (int m = 0; m < 2; ++m)
#pragma unroll
          for (int r = 0; r < 16; ++r) {
            s[m][r] = exp2f(s[m][r] - mnew);
            ps += s[m][r];
          }
        ps += __shfl_xor(ps, 32);
        mrow = mnew;
        lrow = lrow * sc + ps;
        if (!__all(sc == 1.f)) {
#pragma unroll
          for (int db = 0; db < 4; ++db)
#pragma unroll
            for (int r = 0; r < 16; ++r) o[db][r] *= sc;
        }

        u16x8 pa[4];
#pragma unroll
        for (int m = 0; m < 2; ++m) {
          uint32_t pw[4][2];
#pragma unroll
          for (int a = 0; a < 4; ++a)
#pragma unroll
            for (int hh = 0; hh < 2; ++hh)
              pw[a][hh] = (uint32_t)f2bfn(s[m][4 * a + 2 * hh]) |
                          ((uint32_t)f2bfn(s[m][4 * a + 2 * hh + 1]) << 16);
#pragma unroll
          for (int c = 0; c < 2; ++c) {
            uint32_t wd[4];
#pragma unroll
            for (int hh = 0; hh < 2; ++hh) {
              const uint32_t mine  = b5 ? pw[2 * c + 1][hh] : pw[2 * c][hh];
              const uint32_t yours = b5 ? pw[2 * c][hh] : pw[2 * c + 1][hh];
              const uint32_t x = (uint32_t)__shfl_xor((int)yours, 32);
              wd[hh] = b5 ? x : mine;
              wd[2 + hh] = b5 ? mine : x;
            }
            u32x4 tmp = {wd[0], wd[1], wd[2], wd[3]};
            pa[2 * m + c] = __builtin_bit_cast(u16x8, tmp);
          }
        }

        __builtin_amdgcn_s_setprio(1);
#pragma unroll
        for (int db = 0; db < 4; ++db) {
#pragma unroll
          for (int kf = 0; kf < 4; ++kf) {
            u16x8 vf = *(const u16x8*)&Vs[cur][(32 * db + ql) * 64 +
                                              ((kf * 16 + b5 * 8) ^ swz)];
            o[db] = mfma32(vf, pa[kf], o[db]);
          }
        }
        __builtin_amdgcn_s_setprio(0);
      }
      __syncthreads();
      cur ^= 1;
    }

    uint16_t* Yp = Y + ((size_t)(b * T + row0 + ql)) * 2048 + h * 128 + b5 * 4;
    const float inv = 1.f / lrow;
#pragma unroll
    for (int db = 0; db < 4; ++db)
#pragma unroll
      for (int a = 0; a < 4; ++a) {
        u16x4v pk;
#pragma unroll
        for (int r = 0; r < 4; ++r) pk[r] = f2bfn(o[db][4 * a + r] * inv);
        *(u16x4v*)&Yp[db * 32 + a * 8] = pk;
      }
  }
}

extern "C" void kernel_launch(void* const* d_in, const int* in_sizes, int n_in,
                              void* d_out, int out_size, void* d_ws, size_t ws_size,
                              hipStream_t stream) {
  const float* x      = (const float*)d_in[0];
  const float* W_attn = (const float*)d_in[1];
  const float* b_attn = (const float*)d_in[2];
  const float* W_proj = (const float*)d_in[3];
  const float* b_proj = (const float*)d_in[4];
  float* out = (float*)d_out;

  const int B = 4, T = 2048, C = 2048, H = 16, HKV = 4, HS = 128;
  const int M = B * T;               // 8192
  const int Nqkv = C + 2 * HKV * HS; // 3072

  uint8_t* ws = (uint8_t*)d_ws;
  size_t off = 0;
  auto alloc = [&](size_t bytes) {
    void* p = ws + off;
    off += (bytes + 255) & ~(size_t)255;
    return p;
  };
  uint16_t* xb  = (uint16_t*)alloc((size_t)M * C * 2);      // reused as yb after qkv
  uint16_t* WaT = (uint16_t*)alloc((size_t)Nqkv * C * 2);
  uint16_t* WpT = (uint16_t*)alloc((size_t)C * C * 2);
  uint16_t* qb  = (uint16_t*)alloc((size_t)B * H * T * HS * 2);
  uint16_t* kb  = (uint16_t*)alloc((size_t)B * HKV * T * HS * 2);
  uint16_t* vb  = (uint16_t*)alloc((size_t)B * HKV * T * HS * 2);
  uint16_t* vtb = (uint16_t*)alloc((size_t)B * HKV * HS * T * 2);
  uint16_t* yb  = xb;

  cvt_f32_bf16<<<2048, 256, 0, stream>>>(x, xb, M * C / 4);
  transp_cvt<<<dim3(Nqkv / 64, C / 64), 256, 0, stream>>>(W_attn, WaT, C, Nqkv);
  transp_cvt<<<dim3(C / 64, C / 64), 256, 0, stream>>>(W_proj, WpT, C, C);
  gemm_bt<0><<<dim3((M / 128) * (Nqkv / 128)), 256, 0, stream>>>(
      xb, WaT, b_attn, nullptr, qb, kb, vb, M, Nqkv, C);
  transp_v<<<dim3(T / 64, 2, B * HKV), 256, 0, stream>>>(vb, vtb, T);
  attn_fwd<<<dim3(4, H, B), 512, 0, stream>>>(qb, kb, vtb, yb, T);
  gemm_bt<1><<<dim3((M / 128) * (C / 128)), 256, 0, stream>>>(
      yb, WpT, b_proj, out, nullptr, nullptr, nullptr, M, C, C);
}

// Round 11
// 353.907 us; speedup vs baseline: 1.6564x; 1.0416x over previous
//
#include <hip/hip_runtime.h>
#include <stdint.h>

#define DEVI __device__ __forceinline__

typedef __attribute__((ext_vector_type(8))) uint16_t u16x8;
typedef __attribute__((ext_vector_type(4))) uint16_t u16x4v;
typedef __attribute__((ext_vector_type(4))) uint32_t u32x4;
typedef __attribute__((ext_vector_type(8))) __bf16 bf16x8;
typedef __attribute__((ext_vector_type(4))) float f32x4;
typedef __attribute__((ext_vector_type(16))) float f32x16;

DEVI uint16_t f2bf(float x) {
  union { float f; uint32_t u; } v; v.f = x;
  return (uint16_t)((v.u + 0x7fffu + ((v.u >> 16) & 1u)) >> 16);
}

DEVI uint16_t f2bfn(float f) {
  __bf16 h = (__bf16)f;
  return __builtin_bit_cast(uint16_t, h);
}

DEVI f32x4 mfma16(u16x8 a, u16x8 b, f32x4 c) {
  return __builtin_amdgcn_mfma_f32_16x16x32_bf16(
      __builtin_bit_cast(bf16x8, a), __builtin_bit_cast(bf16x8, b), c, 0, 0, 0);
}

DEVI f32x16 mfma32(u16x8 a, u16x8 b, f32x16 c) {
  return __builtin_amdgcn_mfma_f32_32x32x16_bf16(
      __builtin_bit_cast(bf16x8, a), __builtin_bit_cast(bf16x8, b), c, 0, 0, 0);
}

DEVI void async16(void* lds, const void* g) {
  __builtin_amdgcn_global_load_lds(
      (const __attribute__((address_space(1))) uint32_t*)g,
      (__attribute__((address_space(3))) uint32_t*)lds, 16, 0, 0);
}

// 1/sqrt(128) * log2(e): softmax computed in exp2 domain, scale folded into Q.
#define QSC 0.12751742925f

// ---------------- elementwise f32 -> bf16 ----------------
__global__ void cvt_f32_bf16(const float* __restrict__ in, uint16_t* __restrict__ out, int n4) {
  int i = blockIdx.x * blockDim.x + threadIdx.x;
  const int st = gridDim.x * blockDim.x;
  for (; i < n4; i += st) {
    float4 v = ((const float4*)in)[i];
    u16x4v o;
    o[0] = f2bf(v.x); o[1] = f2bf(v.y); o[2] = f2bf(v.z); o[3] = f2bf(v.w);
    ((u16x4v*)out)[i] = o;
  }
}

// ------------- transpose + convert: f32 [K][N] -> bf16 [N][K] -------------
__global__ void transp_cvt(const float* __restrict__ in, uint16_t* __restrict__ out,
                           int K, int N) {
  __shared__ float Ws[64][65];
  const int n0 = blockIdx.x * 64, k0 = blockIdx.y * 64;
  const int t = threadIdx.x;
  const int r = t >> 4, c = (t & 15) << 2;
#pragma unroll
  for (int it = 0; it < 4; ++it) {
    float4 v = *(const float4*)&in[(size_t)(k0 + it * 16 + r) * N + n0 + c];
    Ws[it * 16 + r][c] = v.x; Ws[it * 16 + r][c + 1] = v.y;
    Ws[it * 16 + r][c + 2] = v.z; Ws[it * 16 + r][c + 3] = v.w;
  }
  __syncthreads();
#pragma unroll
  for (int it = 0; it < 4; ++it) {
    const int rr = it * 16 + r;   // n index in tile
    const int cc = c;             // k index in tile
    ushort4 o;
    o.x = f2bf(Ws[cc][rr]);     o.y = f2bf(Ws[cc + 1][rr]);
    o.z = f2bf(Ws[cc + 2][rr]); o.w = f2bf(Ws[cc + 3][rr]);
    *(ushort4*)&out[(size_t)(n0 + rr) * K + k0 + cc] = o;
  }
}

// ---- transpose bf16: [BH][T][128] -> [BH][128][T] (plain layout) ----
__global__ void transp_v(const uint16_t* __restrict__ in, uint16_t* __restrict__ out, int T) {
  __shared__ uint16_t Vsm[64][72];
  const int t0 = blockIdx.x * 64, d0 = blockIdx.y * 64, bh = blockIdx.z;
  const uint16_t* ip = in + (size_t)bh * T * 128;
  uint16_t* op = out + (size_t)bh * 128 * T;
  const int t = threadIdx.x;
  const int r = t >> 3, c = (t & 7) << 3;
#pragma unroll
  for (int it = 0; it < 2; ++it) {
    u16x8 v = *(const u16x8*)&ip[(size_t)(t0 + it * 32 + r) * 128 + d0 + c];
#pragma unroll
    for (int j = 0; j < 8; ++j) Vsm[it * 32 + r][c + j] = v[j];
  }
  __syncthreads();
#pragma unroll
  for (int it = 0; it < 2; ++it) {
    const int rr = it * 32 + r;  // d index in tile
    const int cc = c;            // t index in tile
    u16x8 o;
#pragma unroll
    for (int j = 0; j < 8; ++j) o[j] = Vsm[cc + j][rr];
    *(u16x8*)&op[(size_t)(d0 + rr) * T + t0 + cc] = o;
  }
}

// ------------- GEMM: 8-phase 256x256 schedule (T2+T3+T4+T5) -------------
// BM=BN=256, BK=64, 8 waves (2M x 4N), LDS = 2 bufs x (A 32K + B 32K) = 128KB.
// Per K-tile t (buf = t&1), 4 phases, each: {ds_read A-quad (+ all B frags in
// phase 0) ; stage one half-tile ; [phase 3: counted vmcnt] ; s_barrier ;
// setprio(1) 16 MFMA setprio(0) ; s_barrier}. RAW s_barrier (not
// __syncthreads) so no vmcnt(0) drain in the loop.
// Staging stream: A(t+1) -> buf^1 (phases 0,1); B(t+2) -> B(t)'s space in buf
// (phases 2,3 — B(t) is register-resident after phase 0, so its LDS is dead;
// the glds is issued >=2 barriers after the last B(t) ds_read of any wave).
// vmcnt(4) at phase 3 guarantees (per wave, then barrier makes it global):
// all loads older than the newest 4 (=B(t+2)) landed -> A(t+1) resident.
// B(t+1) was proven resident by the PREVIOUS tile's vmcnt(4) (its loads are
// older than that tile's newest 4). Tail: vmcnt(0) when t+2>=nt.
// T2 chunk swizzle: row r's logical 16B k-chunk c stored at phys c^(r&7)
// (glds dest linear, global source col inverse-swizzled; ds_read XORs back).
// EPI==0: scatter bf16 into q (scaled by QSC) / k / v. EPI==1: f32 out.
template <int EPI>
__global__ __launch_bounds__(512, 1)
void gemm_bt(const uint16_t* __restrict__ A, const uint16_t* __restrict__ Bt,
             const float* __restrict__ bias, float* __restrict__ outF,
             uint16_t* __restrict__ q, uint16_t* __restrict__ kk, uint16_t* __restrict__ v,
             int M, int N, int K) {
  constexpr int BK = 64;
  __shared__ uint16_t As[2][256 * BK];   // [buf][row*64 + physchunk*8], 64 KB
  __shared__ uint16_t Bs[2][256 * BK];   // 64 KB
  // bijective XCD swizzle (grids are multiples of 8)
  int bid = (int)blockIdx.x;
  const int q8 = (int)gridDim.x >> 3;
  bid = (bid & 7) * q8 + (bid >> 3);
  const int nbn = N >> 8;
  const int brow = (bid / nbn) << 8;
  const int bcol = (bid % nbn) << 8;
  const int t = threadIdx.x;
  const int wid = t >> 6, lane = t & 63;
  const int wm = wid >> 2, wn = wid & 3;          // 2 x 4 wave grid
  const int lr = lane & 15, g = lane >> 4;
  const int l7 = lr & 7;

  // --- staging geometry: flat slot = l*512 + t (l=0,1); row = flat>>3,
  // physchunk = flat&7; logical chunk = phys ^ (row&7); (row&7)==((t>>3)&7)
  // for both l since 512/8=64 is a multiple of 8.
  const int sr0 = t >> 3;                          // 0..63
  const int logch = (((t & 7) ^ ((t >> 3) & 7)) << 3);  // element offset
  const uint16_t* Asrc0 = A + (size_t)(brow + sr0) * K + logch;
  const uint16_t* Asrc1 = A + (size_t)(brow + 64 + sr0) * K + logch;
  const uint16_t* Bsrc0 = Bt + (size_t)(bcol + sr0) * K + logch;
  const uint16_t* Bsrc1 = Bt + (size_t)(bcol + 64 + sr0) * K + logch;
  const size_t hskip = (size_t)128 * K;            // half-tile row skip
  const int d0 = t * 8, d1 = 4096 + t * 8;         // linear LDS dest (elements)

  auto stageA = [&](int buf, int h, int k0) {
    async16(&As[buf][h * 8192 + d0], Asrc0 + (size_t)h * hskip + k0);
    async16(&As[buf][h * 8192 + d1], Asrc1 + (size_t)h * hskip + k0);
  };
  auto stageB = [&](int buf, int h, int k0) {
    async16(&Bs[buf][h * 8192 + d0], Bsrc0 + (size_t)h * hskip + k0);
    async16(&Bs[buf][h * 8192 + d1], Bsrc1 + (size_t)h * hskip + k0);
  };

  f32x4 acc[8][4];
#pragma unroll
  for (int i = 0; i < 8; ++i)
#pragma unroll
    for (int j = 0; j < 4; ++j) acc[i][j] = f32x4{0.f, 0.f, 0.f, 0.f};

  const int nt = K / BK;
  // prologue: tile0 A+B -> buf0; tile1 B -> buf1; drain once.
  stageA(0, 0, 0); stageA(0, 1, 0);
  stageB(0, 0, 0); stageB(0, 1, 0);
  if (nt > 1) { stageB(1, 0, BK); stageB(1, 1, BK); }
  asm volatile("s_waitcnt vmcnt(0)" ::: "memory");
  __builtin_amdgcn_s_barrier();

  for (int tt = 0; tt < nt; ++tt) {
    const int buf = tt & 1;
    u16x8 bfr[4][2];
#pragma unroll
    for (int p = 0; p < 4; ++p) {
      if (p == 0) {
#pragma unroll
        for (int j = 0; j < 4; ++j) {
          const int brw = wn * 64 + j * 16 + lr;
#pragma unroll
          for (int s = 0; s < 2; ++s)
            bfr[j][s] = *(const u16x8*)&Bs[buf][brw * 64 + ((((s << 2) + g) ^ l7) << 3)];
        }
      }
      u16x8 af[2][2];
#pragma unroll
      for (int ii = 0; ii < 2; ++ii) {
        const int arow = wm * 128 + (p * 2 + ii) * 16 + lr;
#pragma unroll
        for (int s = 0; s < 2; ++s)
          af[ii][s] = *(const u16x8*)&As[buf][arow * 64 + ((((s << 2) + g) ^ l7) << 3)];
      }
      if (p == 0) { if (tt + 1 < nt) stageA(buf ^ 1, 0, (tt + 1) * BK); }
      if (p == 1) { if (tt + 1 < nt) stageA(buf ^ 1, 1, (tt + 1) * BK); }
      if (p == 2) { if (tt + 2 < nt) stageB(buf, 0, (tt + 2) * BK); }
      if (p == 3) {
        if (tt + 2 < nt) {
          stageB(buf, 1, (tt + 2) * BK);
          asm volatile("s_waitcnt vmcnt(4)" ::: "memory");
        } else {
          asm volatile("s_waitcnt vmcnt(0)" ::: "memory");
        }
      }
      __builtin_amdgcn_s_barrier();
      __builtin_amdgcn_s_setprio(1);
#pragma unroll
      for (int ii = 0; ii < 2; ++ii)
#pragma unroll
        for (int j = 0; j < 4; ++j)
#pragma unroll
          for (int s = 0; s < 2; ++s)
            acc[p * 2 + ii][j] = mfma16(af[ii][s], bfr[j][s], acc[p * 2 + ii][j]);
      __builtin_amdgcn_s_setprio(0);
      __builtin_amdgcn_s_barrier();
    }
  }

#pragma unroll
  for (int i = 0; i < 8; ++i) {
#pragma unroll
    for (int j = 0; j < 4; ++j) {
      const int col = bcol + wn * 64 + j * 16 + lr;
      const float bb = bias[col];
#pragma unroll
      for (int r = 0; r < 4; ++r) {
        const int row = brow + wm * 128 + i * 16 + (g << 2) + r;
        const float val = acc[i][j][r] + bb;
        if (EPI == 1) {
          outF[(size_t)row * N + col] = val;
        } else {
          const int b_ = row >> 11, tt2 = row & 2047;
          const int d = col & 127;
          if (col < 2048) {
            const int hh = col >> 7;
            q[((size_t)((b_ * 16 + hh) * 2048 + tt2) << 7) + d] = f2bf(val * QSC);
          } else if (col < 2560) {
            const int hh = (col - 2048) >> 7;
            kk[((size_t)((b_ * 4 + hh) * 2048 + tt2) << 7) + d] = f2bf(val);
          } else {
            const int hh = (col - 2560) >> 7;
            v[((size_t)((b_ * 4 + hh) * 2048 + tt2) << 7) + d] = f2bf(val);
          }
        }
      }
    }
  }
}

// ------------- flash attention (causal, GQA 4:1), 512-thread blocks -------
// (unchanged from round 9/10 — verified)
__global__ __launch_bounds__(512, 1)
void attn_fwd(const uint16_t* __restrict__ Q,   // [B*16][T][128], pre-scaled by QSC
              const uint16_t* __restrict__ Kg,  // [B*4][T][128]
              const uint16_t* __restrict__ Vt,  // [B*4][128][T]
              uint16_t* __restrict__ Y,         // [B*T][2048], col offset h*128
              int T) {
  __shared__ __align__(16) uint16_t Ks[2][64 * 128];   // 32 KB
  __shared__ __align__(16) uint16_t Vs[2][128 * 64];   // 32 KB
  const int pr = blockIdx.x;                  // 0..3
  const int h = blockIdx.y, b = blockIdx.z;
  const int hkv = h >> 2;

  const int t = threadIdx.x, w = t >> 6, lane = t & 63;
  const int ql = lane & 31, b5 = lane >> 5;
  const int swz = (ql & 7) << 3;

  const uint16_t* Qh = Q + (size_t)(b * 16 + h) * T * 128;
  const uint16_t* Kp = Kg + (size_t)(b * 4 + hkv) * T * 128;
  const uint16_t* Vp = Vt + (size_t)(b * 4 + hkv) * 128 * T;

  auto stage = [&](int buf, int kv0) {
#pragma unroll
    for (int it = 0; it < 2; ++it) {
      const int krow = it * 32 + w * 4 + (lane >> 4);         // 0..63
      const int kcol = ((lane & 15) << 3) ^ ((krow & 7) << 3);
      async16(&Ks[buf][(it * 32 + w * 4) * 128 + lane * 8],
              &Kp[(size_t)(kv0 + krow) * 128 + kcol]);
    }
#pragma unroll
    for (int it = 0; it < 2; ++it) {
      const int vrow = it * 64 + w * 8 + (lane >> 3);         // 0..127
      const int vcol = ((lane & 7) << 3) ^ ((vrow & 7) << 3);
      async16(&Vs[buf][(it * 64 + w * 8) * 64 + lane * 8],
              &Vp[(size_t)vrow * T + kv0 + vcol]);
    }
  };

  for (int half = 0; half < 2; ++half) {
    const int qb = half == 0 ? 7 - pr : pr;                   // 256-row blocks
    const uint16_t* Qp = Qh + (size_t)(qb * 256) * 128;
    const int row0 = qb * 256 + w * 32;
    const int qrow = row0 + ql;

    u16x8 qf[8];
#pragma unroll
    for (int kc = 0; kc < 8; ++kc)
      qf[kc] = *(const u16x8*)&Qp[(size_t)(w * 32 + ql) * 128 + kc * 16 + b5 * 8];

    f32x16 o[4];
#pragma unroll
    for (int db = 0; db < 4; ++db)
#pragma unroll
      for (int r = 0; r < 16; ++r) o[db][r] = 0.f;
    float mrow = -3e38f, lrow = 0.f;

    const int ntiles = 4 * qb + 4;
    const int myn = 4 * qb + (w >> 1) + 1;  // waves skip fully-masked tail tiles

    stage(0, 0);
    __syncthreads();

    int cur = 0;
    for (int tile = 0; tile < ntiles; ++tile) {
      if (tile + 1 < ntiles) stage(cur ^ 1, (tile + 1) << 6);

      if (tile < myn) {
        const int kv0 = tile << 6;
        f32x16 s[2];
#pragma unroll
        for (int m = 0; m < 2; ++m)
#pragma unroll
          for (int r = 0; r < 16; ++r) s[m][r] = 0.f;
        __builtin_amdgcn_s_setprio(1);
#pragma unroll
        for (int kc = 0; kc < 8; ++kc) {
          const int cc = (kc * 16 + b5 * 8) ^ swz;
          u16x8 k0f = *(const u16x8*)&Ks[cur][ql * 128 + cc];
          u16x8 k1f = *(const u16x8*)&Ks[cur][(32 + ql) * 128 + cc];
          s[0] = mfma32(k0f, qf[kc], s[0]);
          s[1] = mfma32(k1f, qf[kc], s[1]);
        }
        __builtin_amdgcn_s_setprio(0);

        if (kv0 + 63 > row0) {
#pragma unroll
          for (int m = 0; m < 2; ++m)
#pragma unroll
            for (int r = 0; r < 16; ++r) {
              const int kg = kv0 + 32 * m + (r & 3) + 8 * (r >> 2) + 4 * b5;
              if (kg > qrow) s[m][r] = -3e38f;
            }
        }
        float mx = s[0][0];
#pragma unroll
        for (int m = 0; m < 2; ++m)
#pragma unroll
          for (int r = 0; r < 16; ++r) mx = fmaxf(mx, s[m][r]);
        mx = fmaxf(mx, __shfl_xor(mx, 32));
        const float mnew = fmaxf(mrow, mx);
        const float sc = exp2f(mrow - mnew);
        float ps = 0.f;
#pragma unroll
        for (int m = 0; m < 2; ++m)
#pragma unroll
          for (int r = 0; r < 16; ++r) {
            s[m][r] = exp2f(s[m][r] - mnew);
            ps += s[m][r];
          }
        ps += __shfl_xor(ps, 32);
        mrow = mnew;
        lrow = lrow * sc + ps;
        if (!__all(sc == 1.f)) {
#pragma unroll
          for (int db = 0; db < 4; ++db)
#pragma unroll
            for (int r = 0; r < 16; ++r) o[db][r] *= sc;
        }

        u16x8 pa[4];
#pragma unroll
        for (int m = 0; m < 2; ++m) {
          uint32_t pw[4][2];
#pragma unroll
          for (int a = 0; a < 4; ++a)
#pragma unroll
            for (int hh = 0; hh < 2; ++hh)
              pw[a][hh] = (uint32_t)f2bfn(s[m][4 * a + 2 * hh]) |
                          ((uint32_t)f2bfn(s[m][4 * a + 2 * hh + 1]) << 16);
#pragma unroll
          for (int c = 0; c < 2; ++c) {
            uint32_t wd[4];
#pragma unroll
            for (int hh = 0; hh < 2; ++hh) {
              const uint32_t mine  = b5 ? pw[2 * c + 1][hh] : pw[2 * c][hh];
              const uint32_t yours = b5 ? pw[2 * c][hh] : pw[2 * c + 1][hh];
              const uint32_t x = (uint32_t)__shfl_xor((int)yours, 32);
              wd[hh] = b5 ? x : mine;
              wd[2 + hh] = b5 ? mine : x;
            }
            u32x4 tmp = {wd[0], wd[1], wd[2], wd[3]};
            pa[2 * m + c] = __builtin_bit_cast(u16x8, tmp);
          }
        }

        __builtin_amdgcn_s_setprio(1);
#pragma unroll
        for (int db = 0; db < 4; ++db) {
#pragma unroll
          for (int kf = 0; kf < 4; ++kf) {
            u16x8 vf = *(const u16x8*)&Vs[cur][(32 * db + ql) * 64 +
                                              ((kf * 16 + b5 * 8) ^ swz)];
            o[db] = mfma32(vf, pa[kf], o[db]);
          }
        }
        __builtin_amdgcn_s_setprio(0);
      }
      __syncthreads();
      cur ^= 1;
    }

    uint16_t* Yp = Y + ((size_t)(b * T + row0 + ql)) * 2048 + h * 128 + b5 * 4;
    const float inv = 1.f / lrow;
#pragma unroll
    for (int db = 0; db < 4; ++db)
#pragma unroll
      for (int a = 0; a < 4; ++a) {
        u16x4v pk;
#pragma unroll
        for (int r = 0; r < 4; ++r) pk[r] = f2bfn(o[db][4 * a + r] * inv);
        *(u16x4v*)&Yp[db * 32 + a * 8] = pk;
      }
  }
}

extern "C" void kernel_launch(void* const* d_in, const int* in_sizes, int n_in,
                              void* d_out, int out_size, void* d_ws, size_t ws_size,
                              hipStream_t stream) {
  const float* x      = (const float*)d_in[0];
  const float* W_attn = (const float*)d_in[1];
  const float* b_attn = (const float*)d_in[2];
  const float* W_proj = (const float*)d_in[3];
  const float* b_proj = (const float*)d_in[4];
  float* out = (float*)d_out;

  const int B = 4, T = 2048, C = 2048, H = 16, HKV = 4, HS = 128;
  const int M = B * T;               // 8192
  const int Nqkv = C + 2 * HKV * HS; // 3072

  uint8_t* ws = (uint8_t*)d_ws;
  size_t off = 0;
  auto alloc = [&](size_t bytes) {
    void* p = ws + off;
    off += (bytes + 255) & ~(size_t)255;
    return p;
  };
  uint16_t* xb  = (uint16_t*)alloc((size_t)M * C * 2);      // reused as yb after qkv
  uint16_t* WaT = (uint16_t*)alloc((size_t)Nqkv * C * 2);
  uint16_t* WpT = (uint16_t*)alloc((size_t)C * C * 2);
  uint16_t* qb  = (uint16_t*)alloc((size_t)B * H * T * HS * 2);
  uint16_t* kb  = (uint16_t*)alloc((size_t)B * HKV * T * HS * 2);
  uint16_t* vb  = (uint16_t*)alloc((size_t)B * HKV * T * HS * 2);
  uint16_t* vtb = (uint16_t*)alloc((size_t)B * HKV * HS * T * 2);
  uint16_t* yb  = xb;

  cvt_f32_bf16<<<2048, 256, 0, stream>>>(x, xb, M * C / 4);
  transp_cvt<<<dim3(Nqkv / 64, C / 64), 256, 0, stream>>>(W_attn, WaT, C, Nqkv);
  transp_cvt<<<dim3(C / 64, C / 64), 256, 0, stream>>>(W_proj, WpT, C, C);
  gemm_bt<0><<<dim3((M / 256) * (Nqkv / 256)), 512, 0, stream>>>(
      xb, WaT, b_attn, nullptr, qb, kb, vb, M, Nqkv, C);
  transp_v<<<dim3(T / 64, 2, B * HKV), 256, 0, stream>>>(vb, vtb, T);
  attn_fwd<<<dim3(4, H, B), 512, 0, stream>>>(qb, kb, vtb, yb, T);
  gemm_bt<1><<<dim3((M / 256) * (C / 256)), 512, 0, stream>>>(
      yb, WpT, b_proj, out, nullptr, nullptr, nullptr, M, C, C);
}

// Round 12
// 347.443 us; speedup vs baseline: 1.6872x; 1.0186x over previous
//
#include <hip/hip_runtime.h>
#include <stdint.h>

#define DEVI __device__ __forceinline__

typedef __attribute__((ext_vector_type(8))) uint16_t u16x8;
typedef __attribute__((ext_vector_type(4))) uint16_t u16x4v;
typedef __attribute__((ext_vector_type(4))) uint32_t u32x4;
typedef __attribute__((ext_vector_type(8))) __bf16 bf16x8;
typedef __attribute__((ext_vector_type(4))) float f32x4;
typedef __attribute__((ext_vector_type(16))) float f32x16;

DEVI uint16_t f2bf(float x) {
  union { float f; uint32_t u; } v; v.f = x;
  return (uint16_t)((v.u + 0x7fffu + ((v.u >> 16) & 1u)) >> 16);
}

DEVI uint16_t f2bfn(float f) {
  __bf16 h = (__bf16)f;
  return __builtin_bit_cast(uint16_t, h);
}

DEVI f32x4 mfma16(u16x8 a, u16x8 b, f32x4 c) {
  return __builtin_amdgcn_mfma_f32_16x16x32_bf16(
      __builtin_bit_cast(bf16x8, a), __builtin_bit_cast(bf16x8, b), c, 0, 0, 0);
}

DEVI f32x16 mfma32(u16x8 a, u16x8 b, f32x16 c) {
  return __builtin_amdgcn_mfma_f32_32x32x16_bf16(
      __builtin_bit_cast(bf16x8, a), __builtin_bit_cast(bf16x8, b), c, 0, 0, 0);
}

DEVI void async16(void* lds, const void* g) {
  __builtin_amdgcn_global_load_lds(
      (const __attribute__((address_space(1))) uint32_t*)g,
      (__attribute__((address_space(3))) uint32_t*)lds, 16, 0, 0);
}

// 1/sqrt(128) * log2(e): softmax computed in exp2 domain, scale folded into Q.
#define QSC 0.12751742925f

// ---------------- elementwise f32 -> bf16 ----------------
__global__ void cvt_f32_bf16(const float* __restrict__ in, uint16_t* __restrict__ out, int n4) {
  int i = blockIdx.x * blockDim.x + threadIdx.x;
  const int st = gridDim.x * blockDim.x;
  for (; i < n4; i += st) {
    float4 v = ((const float4*)in)[i];
    u16x4v o;
    o[0] = f2bf(v.x); o[1] = f2bf(v.y); o[2] = f2bf(v.z); o[3] = f2bf(v.w);
    ((u16x4v*)out)[i] = o;
  }
}

// ------------- transpose + convert: f32 [K][N] -> bf16 [N][K] -------------
__global__ void transp_cvt(const float* __restrict__ in, uint16_t* __restrict__ out,
                           int K, int N) {
  __shared__ float Ws[64][65];
  const int n0 = blockIdx.x * 64, k0 = blockIdx.y * 64;
  const int t = threadIdx.x;
  const int r = t >> 4, c = (t & 15) << 2;
#pragma unroll
  for (int it = 0; it < 4; ++it) {
    float4 v = *(const float4*)&in[(size_t)(k0 + it * 16 + r) * N + n0 + c];
    Ws[it * 16 + r][c] = v.x; Ws[it * 16 + r][c + 1] = v.y;
    Ws[it * 16 + r][c + 2] = v.z; Ws[it * 16 + r][c + 3] = v.w;
  }
  __syncthreads();
#pragma unroll
  for (int it = 0; it < 4; ++it) {
    const int rr = it * 16 + r;   // n index in tile
    const int cc = c;             // k index in tile
    ushort4 o;
    o.x = f2bf(Ws[cc][rr]);     o.y = f2bf(Ws[cc + 1][rr]);
    o.z = f2bf(Ws[cc + 2][rr]); o.w = f2bf(Ws[cc + 3][rr]);
    *(ushort4*)&out[(size_t)(n0 + rr) * K + k0 + cc] = o;
  }
}

// ---- transpose bf16: [BH][T][128] -> [BH][128][T] (plain layout) ----
__global__ void transp_v(const uint16_t* __restrict__ in, uint16_t* __restrict__ out, int T) {
  __shared__ uint16_t Vsm[64][72];
  const int t0 = blockIdx.x * 64, d0 = blockIdx.y * 64, bh = blockIdx.z;
  const uint16_t* ip = in + (size_t)bh * T * 128;
  uint16_t* op = out + (size_t)bh * 128 * T;
  const int t = threadIdx.x;
  const int r = t >> 3, c = (t & 7) << 3;
#pragma unroll
  for (int it = 0; it < 2; ++it) {
    u16x8 v = *(const u16x8*)&ip[(size_t)(t0 + it * 32 + r) * 128 + d0 + c];
#pragma unroll
    for (int j = 0; j < 8; ++j) Vsm[it * 32 + r][c + j] = v[j];
  }
  __syncthreads();
#pragma unroll
  for (int it = 0; it < 2; ++it) {
    const int rr = it * 32 + r;  // d index in tile
    const int cc = c;            // t index in tile
    u16x8 o;
#pragma unroll
    for (int j = 0; j < 8; ++j) o[j] = Vsm[cc + j][rr];
    *(u16x8*)&op[(size_t)(d0 + rr) * T + t0 + cc] = o;
  }
}

// ------ qkv GEMM: 8-phase-style 256x128 tile (T2+T3+T4+T5), EPI scatter ------
// BM=256, BN=128, BK=64, 8 waves (4M x 2N, per-wave 64x64), LDS = 96 KB
// (A dbuf 64K + B dbuf 32K) -> 1 block/CU. Grid 32x24 = 768 = EXACTLY 3
// rounds of 256 (round 11's 256^2 grid of 384 was 1.5 rounds -> 25% idle).
// Per K-tile: 2 phases x 16 MFMA. Staging: A(t+1)->buf^1 in phase 0 (4 glds),
// B(t+2)->B(t)'s dead space in phase 1 (2 glds) + counted vmcnt(2): newest 2
// = B(t+2); A(t+1) and (transitively, from the previous tile's wait) B(t+1)
// proven landed. Raw s_barrier -> no vmcnt(0) drain in the loop.
// T2 chunk swizzle: row r's logical 16B chunk c at phys c^(r&7); glds dest
// linear, global source inverse-swizzled, ds_read XORs back.
__global__ __launch_bounds__(512, 1)
void gemm_qkv(const uint16_t* __restrict__ A, const uint16_t* __restrict__ Bt,
              const float* __restrict__ bias,
              uint16_t* __restrict__ q, uint16_t* __restrict__ kk, uint16_t* __restrict__ v,
              int M, int N, int K) {
  constexpr int BK = 64;
  __shared__ uint16_t As[2][256 * BK];   // 64 KB
  __shared__ uint16_t Bs[2][128 * BK];   // 32 KB
  int bid = (int)blockIdx.x;
  const int q8 = (int)gridDim.x >> 3;
  bid = (bid & 7) * q8 + (bid >> 3);
  const int nbn = N >> 7;
  const int brow = (bid / nbn) << 8;
  const int bcol = (bid % nbn) << 7;
  const int t = threadIdx.x;
  const int wid = t >> 6, lane = t & 63;
  const int wm = wid >> 1, wn = wid & 1;          // 4 x 2 wave grid
  const int lr = lane & 15, g = lane >> 4, l7 = lr & 7;

  // staging geometry: flat slot l*512+t -> row = slot>>3, physchunk = slot&7;
  // logical = phys ^ (row&7); row&7 == (t>>3)&7 for all l (l*64 % 8 == 0).
  const int logch = (((t & 7) ^ ((t >> 3) & 7)) << 3);
  const uint16_t* Asrc = A + (size_t)(brow + (t >> 3)) * K + logch;
  const uint16_t* Bsrc = Bt + (size_t)(bcol + (t >> 3)) * K + logch;
  const size_t skip64 = (size_t)64 * K;
  const int dt = t * 8;

  auto stageA = [&](int buf, int k0) {
#pragma unroll
    for (int l = 0; l < 4; ++l)
      async16(&As[buf][l * 4096 + dt], Asrc + (size_t)l * skip64 + k0);
  };
  auto stageB = [&](int buf, int k0) {
#pragma unroll
    for (int l = 0; l < 2; ++l)
      async16(&Bs[buf][l * 4096 + dt], Bsrc + (size_t)l * skip64 + k0);
  };

  f32x4 acc[4][4];
#pragma unroll
  for (int i = 0; i < 4; ++i)
#pragma unroll
    for (int j = 0; j < 4; ++j) acc[i][j] = f32x4{0.f, 0.f, 0.f, 0.f};

  const int nt = K / BK;
  stageA(0, 0); stageB(0, 0);
  if (nt > 1) stageB(1, BK);
  asm volatile("s_waitcnt vmcnt(0)" ::: "memory");
  __builtin_amdgcn_s_barrier();

  for (int tt = 0; tt < nt; ++tt) {
    const int buf = tt & 1;
    u16x8 bfr[4][2];
#pragma unroll
    for (int p = 0; p < 2; ++p) {
      if (p == 0) {
#pragma unroll
        for (int j = 0; j < 4; ++j) {
          const int brw = wn * 64 + j * 16 + lr;
#pragma unroll
          for (int s = 0; s < 2; ++s)
            bfr[j][s] = *(const u16x8*)&Bs[buf][brw * 64 + ((((s << 2) + g) ^ l7) << 3)];
        }
      }
      u16x8 af[2][2];
#pragma unroll
      for (int ii = 0; ii < 2; ++ii) {
        const int arow = wm * 64 + (p * 2 + ii) * 16 + lr;
#pragma unroll
        for (int s = 0; s < 2; ++s)
          af[ii][s] = *(const u16x8*)&As[buf][arow * 64 + ((((s << 2) + g) ^ l7) << 3)];
      }
      if (p == 0) {
        if (tt + 1 < nt) stageA(buf ^ 1, (tt + 1) * BK);
      } else {
        if (tt + 2 < nt) {
          stageB(buf, (tt + 2) * BK);
          asm volatile("s_waitcnt vmcnt(2)" ::: "memory");
        } else {
          asm volatile("s_waitcnt vmcnt(0)" ::: "memory");
        }
      }
      __builtin_amdgcn_s_barrier();
      __builtin_amdgcn_s_setprio(1);
#pragma unroll
      for (int ii = 0; ii < 2; ++ii)
#pragma unroll
        for (int j = 0; j < 4; ++j)
#pragma unroll
          for (int s = 0; s < 2; ++s)
            acc[p * 2 + ii][j] = mfma16(af[ii][s], bfr[j][s], acc[p * 2 + ii][j]);
      __builtin_amdgcn_s_setprio(0);
      __builtin_amdgcn_s_barrier();
    }
  }

#pragma unroll
  for (int i = 0; i < 4; ++i) {
#pragma unroll
    for (int j = 0; j < 4; ++j) {
      const int col = bcol + wn * 64 + j * 16 + lr;
      const float bb = bias[col];
#pragma unroll
      for (int r = 0; r < 4; ++r) {
        const int row = brow + wm * 64 + i * 16 + (g << 2) + r;
        const float val = acc[i][j][r] + bb;
        const int b_ = row >> 11, tt2 = row & 2047;
        const int d = col & 127;
        if (col < 2048) {
          const int hh = col >> 7;
          q[((size_t)((b_ * 16 + hh) * 2048 + tt2) << 7) + d] = f2bf(val * QSC);
        } else if (col < 2560) {
          const int hh = (col - 2048) >> 7;
          kk[((size_t)((b_ * 4 + hh) * 2048 + tt2) << 7) + d] = f2bf(val);
        } else {
          const int hh = (col - 2560) >> 7;
          v[((size_t)((b_ * 4 + hh) * 2048 + tt2) << 7) + d] = f2bf(val);
        }
      }
    }
  }
}

// ------------- proj GEMM: 8-phase 256x256 schedule (round-11, verified) -----
// Grid 32x8 = 256 = exactly 1 round. See round-11 comments for the vmcnt(4)
// invariant chain.
__global__ __launch_bounds__(512, 1)
void gemm_proj(const uint16_t* __restrict__ A, const uint16_t* __restrict__ Bt,
               const float* __restrict__ bias, float* __restrict__ outF,
               int M, int N, int K) {
  constexpr int BK = 64;
  __shared__ uint16_t As[2][256 * BK];   // 64 KB
  __shared__ uint16_t Bs[2][256 * BK];   // 64 KB
  int bid = (int)blockIdx.x;
  const int q8 = (int)gridDim.x >> 3;
  bid = (bid & 7) * q8 + (bid >> 3);
  const int nbn = N >> 8;
  const int brow = (bid / nbn) << 8;
  const int bcol = (bid % nbn) << 8;
  const int t = threadIdx.x;
  const int wid = t >> 6, lane = t & 63;
  const int wm = wid >> 2, wn = wid & 3;          // 2 x 4 wave grid
  const int lr = lane & 15, g = lane >> 4;
  const int l7 = lr & 7;

  const int sr0 = t >> 3;
  const int logch = (((t & 7) ^ ((t >> 3) & 7)) << 3);
  const uint16_t* Asrc0 = A + (size_t)(brow + sr0) * K + logch;
  const uint16_t* Asrc1 = A + (size_t)(brow + 64 + sr0) * K + logch;
  const uint16_t* Bsrc0 = Bt + (size_t)(bcol + sr0) * K + logch;
  const uint16_t* Bsrc1 = Bt + (size_t)(bcol + 64 + sr0) * K + logch;
  const size_t hskip = (size_t)128 * K;
  const int d0 = t * 8, d1 = 4096 + t * 8;

  auto stageA = [&](int buf, int h, int k0) {
    async16(&As[buf][h * 8192 + d0], Asrc0 + (size_t)h * hskip + k0);
    async16(&As[buf][h * 8192 + d1], Asrc1 + (size_t)h * hskip + k0);
  };
  auto stageB = [&](int buf, int h, int k0) {
    async16(&Bs[buf][h * 8192 + d0], Bsrc0 + (size_t)h * hskip + k0);
    async16(&Bs[buf][h * 8192 + d1], Bsrc1 + (size_t)h * hskip + k0);
  };

  f32x4 acc[8][4];
#pragma unroll
  for (int i = 0; i < 8; ++i)
#pragma unroll
    for (int j = 0; j < 4; ++j) acc[i][j] = f32x4{0.f, 0.f, 0.f, 0.f};

  const int nt = K / BK;
  stageA(0, 0, 0); stageA(0, 1, 0);
  stageB(0, 0, 0); stageB(0, 1, 0);
  if (nt > 1) { stageB(1, 0, BK); stageB(1, 1, BK); }
  asm volatile("s_waitcnt vmcnt(0)" ::: "memory");
  __builtin_amdgcn_s_barrier();

  for (int tt = 0; tt < nt; ++tt) {
    const int buf = tt & 1;
    u16x8 bfr[4][2];
#pragma unroll
    for (int p = 0; p < 4; ++p) {
      if (p == 0) {
#pragma unroll
        for (int j = 0; j < 4; ++j) {
          const int brw = wn * 64 + j * 16 + lr;
#pragma unroll
          for (int s = 0; s < 2; ++s)
            bfr[j][s] = *(const u16x8*)&Bs[buf][brw * 64 + ((((s << 2) + g) ^ l7) << 3)];
        }
      }
      u16x8 af[2][2];
#pragma unroll
      for (int ii = 0; ii < 2; ++ii) {
        const int arow = wm * 128 + (p * 2 + ii) * 16 + lr;
#pragma unroll
        for (int s = 0; s < 2; ++s)
          af[ii][s] = *(const u16x8*)&As[buf][arow * 64 + ((((s << 2) + g) ^ l7) << 3)];
      }
      if (p == 0) { if (tt + 1 < nt) stageA(buf ^ 1, 0, (tt + 1) * BK); }
      if (p == 1) { if (tt + 1 < nt) stageA(buf ^ 1, 1, (tt + 1) * BK); }
      if (p == 2) { if (tt + 2 < nt) stageB(buf, 0, (tt + 2) * BK); }
      if (p == 3) {
        if (tt + 2 < nt) {
          stageB(buf, 1, (tt + 2) * BK);
          asm volatile("s_waitcnt vmcnt(4)" ::: "memory");
        } else {
          asm volatile("s_waitcnt vmcnt(0)" ::: "memory");
        }
      }
      __builtin_amdgcn_s_barrier();
      __builtin_amdgcn_s_setprio(1);
#pragma unroll
      for (int ii = 0; ii < 2; ++ii)
#pragma unroll
        for (int j = 0; j < 4; ++j)
#pragma unroll
          for (int s = 0; s < 2; ++s)
            acc[p * 2 + ii][j] = mfma16(af[ii][s], bfr[j][s], acc[p * 2 + ii][j]);
      __builtin_amdgcn_s_setprio(0);
      __builtin_amdgcn_s_barrier();
    }
  }

#pragma unroll
  for (int i = 0; i < 8; ++i) {
#pragma unroll
    for (int j = 0; j < 4; ++j) {
      const int col = bcol + wn * 64 + j * 16 + lr;
      const float bb = bias[col];
#pragma unroll
      for (int r = 0; r < 4; ++r) {
        const int row = brow + wm * 128 + i * 16 + (g << 2) + r;
        outF[(size_t)row * N + col] = acc[i][j][r] + bb;
      }
    }
  }
}

// ------------- flash attention (causal, GQA 4:1), 512-thread blocks -------
// (unchanged from round 9/10/11 — verified)
__global__ __launch_bounds__(512, 1)
void attn_fwd(const uint16_t* __restrict__ Q,   // [B*16][T][128], pre-scaled by QSC
              const uint16_t* __restrict__ Kg,  // [B*4][T][128]
              const uint16_t* __restrict__ Vt,  // [B*4][128][T]
              uint16_t* __restrict__ Y,         // [B*T][2048], col offset h*128
              int T) {
  __shared__ __align__(16) uint16_t Ks[2][64 * 128];   // 32 KB
  __shared__ __align__(16) uint16_t Vs[2][128 * 64];   // 32 KB
  const int pr = blockIdx.x;                  // 0..3
  const int h = blockIdx.y, b = blockIdx.z;
  const int hkv = h >> 2;

  const int t = threadIdx.x, w = t >> 6, lane = t & 63;
  const int ql = lane & 31, b5 = lane >> 5;
  const int swz = (ql & 7) << 3;

  const uint16_t* Qh = Q + (size_t)(b * 16 + h) * T * 128;
  const uint16_t* Kp = Kg + (size_t)(b * 4 + hkv) * T * 128;
  const uint16_t* Vp = Vt + (size_t)(b * 4 + hkv) * 128 * T;

  auto stage = [&](int buf, int kv0) {
#pragma unroll
    for (int it = 0; it < 2; ++it) {
      const int krow = it * 32 + w * 4 + (lane >> 4);         // 0..63
      const int kcol = ((lane & 15) << 3) ^ ((krow & 7) << 3);
      async16(&Ks[buf][(it * 32 + w * 4) * 128 + lane * 8],
              &Kp[(size_t)(kv0 + krow) * 128 + kcol]);
    }
#pragma unroll
    for (int it = 0; it < 2; ++it) {
      const int vrow = it * 64 + w * 8 + (lane >> 3);         // 0..127
      const int vcol = ((lane & 7) << 3) ^ ((vrow & 7) << 3);
      async16(&Vs[buf][(it * 64 + w * 8) * 64 + lane * 8],
              &Vp[(size_t)vrow * T + kv0 + vcol]);
    }
  };

  for (int half = 0; half < 2; ++half) {
    const int qb = half == 0 ? 7 - pr : pr;                   // 256-row blocks
    const uint16_t* Qp = Qh + (size_t)(qb * 256) * 128;
    const int row0 = qb * 256 + w * 32;
    const int qrow = row0 + ql;

    u16x8 qf[8];
#pragma unroll
    for (int kc = 0; kc < 8; ++kc)
      qf[kc] = *(const u16x8*)&Qp[(size_t)(w * 32 + ql) * 128 + kc * 16 + b5 * 8];

    f32x16 o[4];
#pragma unroll
    for (int db = 0; db < 4; ++db)
#pragma unroll
      for (int r = 0; r < 16; ++r) o[db][r] = 0.f;
    float mrow = -3e38f, lrow = 0.f;

    const int ntiles = 4 * qb + 4;
    const int myn = 4 * qb + (w >> 1) + 1;  // waves skip fully-masked tail tiles

    stage(0, 0);
    __syncthreads();

    int cur = 0;
    for (int tile = 0; tile < ntiles; ++tile) {
      if (tile + 1 < ntiles) stage(cur ^ 1, (tile + 1) << 6);

      if (tile < myn) {
        const int kv0 = tile << 6;
        f32x16 s[2];
#pragma unroll
        for (int m = 0; m < 2; ++m)
#pragma unroll
          for (int r = 0; r < 16; ++r) s[m][r] = 0.f;
        __builtin_amdgcn_s_setprio(1);
#pragma unroll
        for (int kc = 0; kc < 8; ++kc) {
          const int cc = (kc * 16 + b5 * 8) ^ swz;
          u16x8 k0f = *(const u16x8*)&Ks[cur][ql * 128 + cc];
          u16x8 k1f = *(const u16x8*)&Ks[cur][(32 + ql) * 128 + cc];
          s[0] = mfma32(k0f, qf[kc], s[0]);
          s[1] = mfma32(k1f, qf[kc], s[1]);
        }
        __builtin_amdgcn_s_setprio(0);

        if (kv0 + 63 > row0) {
#pragma unroll
          for (int m = 0; m < 2; ++m)
#pragma unroll
            for (int r = 0; r < 16; ++r) {
              const int kg = kv0 + 32 * m + (r & 3) + 8 * (r >> 2) + 4 * b5;
              if (kg > qrow) s[m][r] = -3e38f;
            }
        }
        float mx = s[0][0];
#pragma unroll
        for (int m = 0; m < 2; ++m)
#pragma unroll
          for (int r = 0; r < 16; ++r) mx = fmaxf(mx, s[m][r]);
        mx = fmaxf(mx, __shfl_xor(mx, 32));
        const float mnew = fmaxf(mrow, mx);
        const float sc = exp2f(mrow - mnew);
        float ps = 0.f;
#pragma unroll
        for (int m = 0; m < 2; ++m)
#pragma unroll
          for (int r = 0; r < 16; ++r) {
            s[m][r] = exp2f(s[m][r] - mnew);
            ps += s[m][r];
          }
        ps += __shfl_xor(ps, 32);
        mrow = mnew;
        lrow = lrow * sc + ps;
        if (!__all(sc == 1.f)) {
#pragma unroll
          for (int db = 0; db < 4; ++db)
#pragma unroll
            for (int r = 0; r < 16; ++r) o[db][r] *= sc;
        }

        u16x8 pa[4];
#pragma unroll
        for (int m = 0; m < 2; ++m) {
          uint32_t pw[4][2];
#pragma unroll
          for (int a = 0; a < 4; ++a)
#pragma unroll
            for (int hh = 0; hh < 2; ++hh)
              pw[a][hh] = (uint32_t)f2bfn(s[m][4 * a + 2 * hh]) |
                          ((uint32_t)f2bfn(s[m][4 * a + 2 * hh + 1]) << 16);
#pragma unroll
          for (int c = 0; c < 2; ++c) {
            uint32_t wd[4];
#pragma unroll
            for (int hh = 0; hh < 2; ++hh) {
              const uint32_t mine  = b5 ? pw[2 * c + 1][hh] : pw[2 * c][hh];
              const uint32_t yours = b5 ? pw[2 * c][hh] : pw[2 * c + 1][hh];
              const uint32_t x = (uint32_t)__shfl_xor((int)yours, 32);
              wd[hh] = b5 ? x : mine;
              wd[2 + hh] = b5 ? mine : x;
            }
            u32x4 tmp = {wd[0], wd[1], wd[2], wd[3]};
            pa[2 * m + c] = __builtin_bit_cast(u16x8, tmp);
          }
        }

        __builtin_amdgcn_s_setprio(1);
#pragma unroll
        for (int db = 0; db < 4; ++db) {
#pragma unroll
          for (int kf = 0; kf < 4; ++kf) {
            u16x8 vf = *(const u16x8*)&Vs[cur][(32 * db + ql) * 64 +
                                              ((kf * 16 + b5 * 8) ^ swz)];
            o[db] = mfma32(vf, pa[kf], o[db]);
          }
        }
        __builtin_amdgcn_s_setprio(0);
      }
      __syncthreads();
      cur ^= 1;
    }

    uint16_t* Yp = Y + ((size_t)(b * T + row0 + ql)) * 2048 + h * 128 + b5 * 4;
    const float inv = 1.f / lrow;
#pragma unroll
    for (int db = 0; db < 4; ++db)
#pragma unroll
      for (int a = 0; a < 4; ++a) {
        u16x4v pk;
#pragma unroll
        for (int r = 0; r < 4; ++r) pk[r] = f2bfn(o[db][4 * a + r] * inv);
        *(u16x4v*)&Yp[db * 32 + a * 8] = pk;
      }
  }
}

extern "C" void kernel_launch(void* const* d_in, const int* in_sizes, int n_in,
                              void* d_out, int out_size, void* d_ws, size_t ws_size,
                              hipStream_t stream) {
  const float* x      = (const float*)d_in[0];
  const float* W_attn = (const float*)d_in[1];
  const float* b_attn = (const float*)d_in[2];
  const float* W_proj = (const float*)d_in[3];
  const float* b_proj = (const float*)d_in[4];
  float* out = (float*)d_out;

  const int B = 4, T = 2048, C = 2048, H = 16, HKV = 4, HS = 128;
  const int M = B * T;               // 8192
  const int Nqkv = C + 2 * HKV * HS; // 3072

  uint8_t* ws = (uint8_t*)d_ws;
  size_t off = 0;
  auto alloc = [&](size_t bytes) {
    void* p = ws + off;
    off += (bytes + 255) & ~(size_t)255;
    return p;
  };
  uint16_t* xb  = (uint16_t*)alloc((size_t)M * C * 2);      // reused as yb after qkv
  uint16_t* WaT = (uint16_t*)alloc((size_t)Nqkv * C * 2);
  uint16_t* WpT = (uint16_t*)alloc((size_t)C * C * 2);
  uint16_t* qb  = (uint16_t*)alloc((size_t)B * H * T * HS * 2);
  uint16_t* kb  = (uint16_t*)alloc((size_t)B * HKV * T * HS * 2);
  uint16_t* vb  = (uint16_t*)alloc((size_t)B * HKV * T * HS * 2);
  uint16_t* vtb = (uint16_t*)alloc((size_t)B * HKV * HS * T * 2);
  uint16_t* yb  = xb;

  cvt_f32_bf16<<<2048, 256, 0, stream>>>(x, xb, M * C / 4);
  transp_cvt<<<dim3(Nqkv / 64, C / 64), 256, 0, stream>>>(W_attn, WaT, C, Nqkv);
  transp_cvt<<<dim3(C / 64, C / 64), 256, 0, stream>>>(W_proj, WpT, C, C);
  gemm_qkv<<<dim3((M / 256) * (Nqkv / 128)), 512, 0, stream>>>(
      xb, WaT, b_attn, qb, kb, vb, M, Nqkv, C);
  transp_v<<<dim3(T / 64, 2, B * HKV), 256, 0, stream>>>(vb, vtb, T);
  attn_fwd<<<dim3(4, H, B), 512, 0, stream>>>(qb, kb, vtb, yb, T);
  gemm_proj<<<dim3((M / 256) * (C / 256)), 512, 0, stream>>>(
      yb, WpT, b_proj, out, M, C, C);
}